// Round 3
// baseline (1321.921 us; speedup 1.0000x reference)
//
#include <hip/hip_runtime.h>
#include <math.h>

#define FD     512
#define NBATCH 16
#define NROWS  16384
#define MM     5
#define LAMV   1e-4f
#define MAXIT  50
#define TOLV   0.01f
#define NTOT   8388608
#define PADW   520             // LDS row stride (bf16 elems), 16B aligned

// persistent-kernel tiling: 32 rows/block, 512 blocks, 2 blocks/CU, 32 waves/CU
#define PROWS  32
#define PNBLK  (NROWS/PROWS)   // 512
#define PTPB   1024            // 16 waves/block
#define BPB    32              // blocks per batch (PNBLK/NBATCH)

// fallback-kernel tiling (proven multi-launch path)
#define ROWS   64
#define NBLK   (NROWS/ROWS)
#define TPB    1024

typedef __attribute__((ext_vector_type(8))) short  short8;   // 8 bf16
typedef __attribute__((ext_vector_type(4))) float  float4v;  // MFMA C/D frag

// Persistent device state; fully rewritten (or provably unused) every call.
__device__ unsigned short g_Fm[MM][NTOT];
__device__ unsigned short g_G [MM][NTOT];
__device__ unsigned short g_xb[NTOT];          // fallback path only
__device__ unsigned short g_Wb [FD*FD];        // bf16(lin_w) row-major
__device__ unsigned short g_WbO[FD*FD];        // bf16(weight) row-major
__device__ float g_acc [MAXIT-2][NBATCH][8];   // per-iter Gram-row dots [0..4], ||f||^2 [5]
__device__ float g_acc0[NBATCH][8];            // init dots d00,d01,d11
// Fence-free barrier state: MONOTONIC counters, never reset (g_done carries the
// completed-barrier base across launches; launches are stream-ordered).
__device__ unsigned g_leaf[NBATCH];            // +BPB per barrier
__device__ unsigned g_root;                    // +NBATCH per barrier
__device__ unsigned g_done;                    // barriers completed, all launches

static __device__ __forceinline__ unsigned short f2bf(float f) {
    unsigned u = __float_as_uint(f);
    u += 0x7fff + ((u >> 16) & 1);             // RNE
    return (unsigned short)(u >> 16);
}
static __device__ __forceinline__ float bf2f(unsigned short s) {
    return __uint_as_float(((unsigned)s) << 16);
}
static __device__ __forceinline__ float aload(const float* p) {
    return __hip_atomic_load(p, __ATOMIC_RELAXED, __HIP_MEMORY_SCOPE_AGENT);
}
static __device__ __forceinline__ void astoref(float* p, float v) {
    __hip_atomic_store(p, v, __ATOMIC_RELAXED, __HIP_MEMORY_SCOPE_AGENT);
}
static __device__ __forceinline__ void astoreu(unsigned* p, unsigned v) {
    __hip_atomic_store(p, v, __ATOMIC_RELAXED, __HIP_MEMORY_SCOPE_AGENT);
}

// ---------- 32x512 tile GEMM, IN-PLACE on As: D = A @ W^T + bias -------------
// 16 waves: wave wv owns cols [wv*32, wv*32+32) (2 ct), rows in 2 r16 groups.
// Accumulator stays in regs until all A-frag LDS reads are done (barrier), so
// the C-write can overwrite As. MODE 0: bf16 -> As. MODE 1: fp32 -> gout.
template<int MODE>
static __device__ __forceinline__ void mfma_ip(const unsigned short* __restrict__ Wb,
                                               const float* __restrict__ bvec,
                                               unsigned short* As,
                                               float* __restrict__ gout)
{
    const int lane = threadIdx.x & 63;
    const int wv   = threadIdx.x >> 6;     // 0..15
    const int lm   = lane & 15;
    const int quad = lane >> 4;
    float4v acc[2][2];
#pragma unroll
    for (int ct = 0; ct < 2; ct++) {
        const float b = bvec[wv*32 + ct*16 + lm];
#pragma unroll
        for (int r16 = 0; r16 < 2; r16++) {
            acc[r16][ct][0]=b; acc[r16][ct][1]=b; acc[r16][ct][2]=b; acc[r16][ct][3]=b;
        }
    }
#pragma unroll
    for (int q = 0; q < 4; q++) {
#pragma unroll
        for (int kb = 0; kb < 4; kb++) {
            const int ko = q*128 + kb*32 + quad*8;
            short8 bf[2];
#pragma unroll
            for (int ct = 0; ct < 2; ct++)
                bf[ct] = *(const short8*)(Wb + (wv*32 + ct*16 + lm)*FD + ko);
            short8 af[2];
#pragma unroll
            for (int r16 = 0; r16 < 2; r16++)
                af[r16] = *(const short8*)(As + (r16*16 + lm)*PADW + ko);
#pragma unroll
            for (int r16 = 0; r16 < 2; r16++) {
                acc[r16][0] = __builtin_amdgcn_mfma_f32_16x16x32_bf16(af[r16], bf[0], acc[r16][0], 0,0,0);
                acc[r16][1] = __builtin_amdgcn_mfma_f32_16x16x32_bf16(af[r16], bf[1], acc[r16][1], 0,0,0);
            }
        }
    }
    if (MODE == 0) __syncthreads();        // all A-reads done before overwrite
#pragma unroll
    for (int ct = 0; ct < 2; ct++) {
        const int c = wv*32 + ct*16 + lm;
#pragma unroll
        for (int r16 = 0; r16 < 2; r16++)
#pragma unroll
            for (int r = 0; r < 4; r++) {
                const int row = r16*16 + quad*4 + r;
                if (MODE == 0) As[row*PADW + c] = f2bf(acc[r16][ct][r]);
                else           gout[row*FD + c] = acc[r16][ct][r];
            }
    }
    if (MODE == 0) __syncthreads();        // C visible to all waves
}

static __device__ __forceinline__ void red6(const float vals[6], float (*redS)[8], float* accrow)
{
    const int lane = threadIdx.x & 63, wv = threadIdx.x >> 6;   // wv 0..15
#pragma unroll
    for (int j = 0; j < 6; j++) {
        float v = vals[j];
#pragma unroll
        for (int o = 32; o; o >>= 1) v += __shfl_down(v, o);
        if (lane == 0) redS[wv][j] = v;
    }
    __syncthreads();
    if (threadIdx.x < 6) {
        float s = 0.f;
#pragma unroll
        for (int w = 0; w < 16; w++) s += redS[w][threadIdx.x];
        atomicAdd(accrow + threadIdx.x, s);   // device-scope
    }
}

// Fence-free device barrier (BPB=32 blocks/leaf, NBATCH=16 leaves).
// __syncthreads drains vmem before leaf arrival; root inc is data-dependent on
// leaf count; no cache maintenance -> block-private L2 lines survive.
#define GBAR() do {                                                                       \
    __syncthreads();                                                                      \
    if (tid == 0) {                                                                       \
        ++nbar;                                                                           \
        const unsigned lt = (bar_base + (unsigned)nbar) * (unsigned)BPB;                  \
        const unsigned rt = (bar_base + (unsigned)nbar) * (unsigned)NBATCH;               \
        const unsigned lv = __hip_atomic_fetch_add(&g_leaf[b], 1u,                        \
                              __ATOMIC_RELAXED, __HIP_MEMORY_SCOPE_AGENT) + 1u;           \
        if (lv == lt)                                                                     \
            __hip_atomic_fetch_add(&g_root, 1u,                                           \
                              __ATOMIC_RELAXED, __HIP_MEMORY_SCOPE_AGENT);                \
        while ((int)(__hip_atomic_load(&g_root, __ATOMIC_RELAXED,                         \
                              __HIP_MEMORY_SCOPE_AGENT) - rt) < 0)                        \
            __builtin_amdgcn_s_sleep(2);                                                  \
    }                                                                                     \
    __syncthreads();                                                                      \
} while (0)

// ======================= persistent cooperative kernel =======================
// 512 blocks x 1024 thr, 2 blocks/CU (32 waves/CU). LDS = As only (~34 KB):
// GEMM runs in-place, x~ lives in registers (16 elems/thread), F lives in As
// across the iteration boundary (pass-1 LDS reuse of slot (k-1)%5).
__global__ void __launch_bounds__(PTPB, 8) k_anderson(
    const float* __restrict__ x,     const float* __restrict__ lin_w,
    const float* __restrict__ lin_b, const float* __restrict__ weight,
    const float* __restrict__ bias,  float* __restrict__ out)
{
    __shared__ __align__(16) unsigned short As[PROWS*PADW];
    __shared__ float redS[16][8];
    __shared__ float gramS[MM][MM];
    __shared__ float alphaS[MM];
    __shared__ float Hs[48];
    __shared__ float gAs[MM][MM];
    __shared__ float ga0S[3];
    __shared__ float sres;

    const int tid  = threadIdx.x;
    const int t    = blockIdx.x, b = t >> 5;       // 32 blocks per batch
    const int base = t * (PROWS*FD);               // 16384 elems/block

    unsigned bar_base = 0; int nbar = 0;
    if (tid == 0)
        bar_base = __hip_atomic_load(&g_done, __ATOMIC_RELAXED, __HIP_MEMORY_SCOPE_AGENT);

    // ---------- phase 0: weights -> bf16 (coherent), zero accs, x -> As+regs --
    if (tid < 256) {                               // 512 blk x 256 = FD*FD/2 pairs
        const int wi = t*256 + tid;
        const float2 w0 = *(const float2*)(lin_w  + 2*wi);
        const float2 w1 = *(const float2*)(weight + 2*wi);
        astoreu((unsigned*)g_Wb  + wi, (unsigned)f2bf(w0.x) | ((unsigned)f2bf(w0.y) << 16));
        astoreu((unsigned*)g_WbO + wi, (unsigned)f2bf(w1.x) | ((unsigned)f2bf(w1.y) << 16));
    } else if (tid < 272) {
        const int zi = t*16 + (tid - 256);         // 8192 >= 6272
        if (zi < (MAXIT-2)*NBATCH*8)               astoref(&g_acc[0][0][0] + zi, 0.f);
        else if (zi < (MAXIT-2)*NBATCH*8 + NBATCH*8)
            astoref(&g_acc0[0][0] + (zi - (MAXIT-2)*NBATCH*8), 0.f);
    }
    short8 xh[2];                                  // this thread's 16 bf16 of x~
#pragma unroll
    for (int i = 0; i < 2; i++) {
        const int e = (i*PTPB + tid) * 8;
        const float4 a0 = *(const float4*)(x + base + e);
        const float4 a1 = *(const float4*)(x + base + e + 4);
        short8 v;
        v[0]=f2bf(a0.x); v[1]=f2bf(a0.y); v[2]=f2bf(a0.z); v[3]=f2bf(a0.w);
        v[4]=f2bf(a1.x); v[5]=f2bf(a1.y); v[6]=f2bf(a1.z); v[7]=f2bf(a1.w);
        xh[i] = v;
        *(short8*)(As + (e>>9)*PADW + (e&511)) = v;
    }
    GBAR();                                        // barrier 1: weights/zeros ready

    // ---------- init: F0=f(x~0), F1=f(F~0), G0, G1, init Gram dots ------------
    mfma_ip<0>(g_Wb, lin_b, As, nullptr);          // As = bf16(F0)
    float d00 = 0.f;
    short8 fh[2];                                  // F0 (for G1 = F1 - F0)
#pragma unroll
    for (int i = 0; i < 2; i++) {
        const int e = (i*PTPB + tid) * 8;
        const int off = base + e, lo = (e>>9)*PADW + (e&511);
        const short8 fv = *(const short8*)(As + lo);
        const short8 xv = xh[i];
        short8 gv;
#pragma unroll
        for (int j = 0; j < 8; j++) {
            const float g = bf2f((unsigned short)fv[j]) - bf2f((unsigned short)xv[j]);
            gv[j] = (short)f2bf(g);
            d00 = fmaf(g, g, d00);
        }
        *(short8*)(&g_Fm[0][off]) = fv;
        *(short8*)(&g_G [0][off]) = gv;
        fh[i] = fv;
    }
    mfma_ip<0>(g_Wb, lin_b, As, nullptr);          // As = bf16(F1)
    float d01 = 0.f, d11 = 0.f;
#pragma unroll
    for (int i = 0; i < 2; i++) {
        const int e = (i*PTPB + tid) * 8;
        const int off = base + e, lo = (e>>9)*PADW + (e&511);
        const short8 f1 = *(const short8*)(As + lo);
        const short8 f0 = fh[i];
        const short8 g0 = *(const short8*)(&g_G[0][off]);
        short8 gv;
#pragma unroll
        for (int j = 0; j < 8; j++) {
            const float g = bf2f((unsigned short)f1[j]) - bf2f((unsigned short)f0[j]);
            gv[j] = (short)f2bf(g);
            d11 = fmaf(g, g, d11);
            d01 = fmaf(bf2f((unsigned short)g0[j]), g, d01);
        }
        *(short8*)(&g_Fm[1][off]) = f1;
        *(short8*)(&g_G [1][off]) = gv;
    }
    {
        const float vals[6] = {d00, d01, d11, 0.f, 0.f, 0.f};
        red6(vals, redS, &g_acc0[b][0]);
    }
    GBAR();                                        // barrier 2: init dots ready

    // ---------------- Anderson iterations (k = 2..49) -------------------------
    for (int k = 2; k < MAXIT; k++) {
        const int it = k - 2, idx = k % MM, nk = (k < MM) ? k : MM;
        const int j0 = (k - 5 > 2) ? (k - 5) : 2;

        if (k > 2 && (tid >> 6) == 0) {            // wave 0: residual of k-1
            float v = 0.f;
            if (tid < 32) {
                const int bb = tid & 15;
                const int jj = (tid < 16) ? ((k-1) % MM) : 5;
                v = aload(&g_acc[it-1][bb][jj]);
            }
            v += __shfl_xor(v, 1); v += __shfl_xor(v, 2);
            v += __shfl_xor(v, 4); v += __shfl_xor(v, 8);
            const float num = __shfl(v, 0), den = __shfl(v, 16);
            if (tid == 0) sres = sqrtf(num) / (1e-5f + sqrtf(den));
        }
        if ((tid >> 6) == 1) {                     // wave 1: Gram window -> LDS
            const int l = tid & 63;
            if (l < 25) {
                const int jj = j0 + l/5;
                if (jj < k) gAs[l/5][l%5] = aload(&g_acc[jj-2][b][l%5]);
            } else if (l < 28) {
                ga0S[l-25] = aload(&g_acc0[b][l-25]);
            }
        }
        __syncthreads();
        if (k > 2 && sres < TOLV) break;           // uniform across grid

        // --- Gram replay + bordered 6x6 solve (lane 0)
        if (tid == 0) {
#pragma unroll
            for (int i = 0; i < MM; i++)
#pragma unroll
                for (int j = 0; j < MM; j++) gramS[i][j] = 0.f;
            gramS[0][0] = ga0S[0];
            gramS[0][1] = gramS[1][0] = ga0S[1];
            gramS[1][1] = ga0S[2];
            for (int j = j0; j < k; j++) {
                const int ij = j % MM, nkj = (j < MM) ? j : MM;
                for (int c = 0; c < MM; c++)
                    if (c < nkj || c == ij) {
                        const float vv = gAs[j - j0][c];
                        gramS[ij][c] = vv; gramS[c][ij] = vv;
                    }
            }
            float* H = Hs;                         // 6x7 augmented
            for (int i = 0; i < 42; i++) H[i] = 0.f;
            for (int j = 0; j < nk; j++) { H[1+j] = 1.f; H[(1+j)*7] = 1.f; }
#pragma unroll
            for (int i = 0; i < MM; i++) H[(1+i)*7 + (1+i)] = LAMV;
            for (int i = 0; i < nk; i++)
                for (int j = 0; j < nk; j++)
                    H[(1+i)*7 + (1+j)] = gramS[i][j] + (i == j ? LAMV : 0.f);
            H[6] = 1.f;                            // rhs = e0
            for (int col = 0; col < 6; col++) {
                int p = col; float mx = fabsf(H[col*7+col]);
                for (int r2 = col+1; r2 < 6; r2++) {
                    const float vv = fabsf(H[r2*7+col]);
                    if (vv > mx) { mx = vv; p = r2; }
                }
                if (p != col)
                    for (int j = col; j < 7; j++) { const float tt = H[col*7+j]; H[col*7+j] = H[p*7+j]; H[p*7+j] = tt; }
                const float piv = H[col*7+col];
                for (int r2 = col+1; r2 < 6; r2++) {
                    const float fct = H[r2*7+col] / piv;
                    for (int j = col+1; j < 7; j++) H[r2*7+j] -= fct * H[col*7+j];
                }
            }
            for (int r2 = 5; r2 >= 0; r2--) {
                float s = H[r2*7+6];
                for (int j = r2+1; j < 6; j++) s -= H[r2*7+j] * H[j*7+6];
                H[r2*7+6] = s / H[r2*7+r2];
            }
#pragma unroll
            for (int m = 0; m < MM; m++) alphaS[m] = H[(1+m)*7+6];
        }
        __syncthreads();

        float al[MM];
#pragma unroll
        for (int m = 0; m < MM; m++) al[m] = alphaS[m];

        // --- pass 1: x~ = bf16(sum_m alpha_m Fm[m]) -> As + xh regs
        // As still holds F_{k-1} = slot (k-1)%MM (at k=2: F1 = slot 1).
        {
            const int sF = (k == 2) ? 1 : ((k - 1) % MM);
#pragma unroll
            for (int i = 0; i < 2; i++) {
                const int e = (i*PTPB + tid) * 8;
                const int off = base + e, lo = (e>>9)*PADW + (e&511);
                const short8 asv = *(const short8*)(As + lo);
                float s[8] = {0,0,0,0,0,0,0,0};
#pragma unroll
                for (int m = 0; m < MM; m++) {
                    if (m < nk) {
                        short8 fm;
                        if (m == sF) fm = asv;
                        else         fm = *(const short8*)(&g_Fm[m][off]);
#pragma unroll
                        for (int j = 0; j < 8; j++)
                            s[j] = fmaf(al[m], bf2f((unsigned short)fm[j]), s[j]);
                    }
                }
                short8 v;
#pragma unroll
                for (int j = 0; j < 8; j++) v[j] = (short)f2bf(s[j]);
                xh[i] = v;
                *(short8*)(As + lo) = v;
            }
        }
        __syncthreads();
        // --- pass 2: As = bf16(x~ @ lin_w^T + lin_b)  (in-place)
        mfma_ip<0>(g_Wb, lin_b, As, nullptr);
        // --- pass 3: state writes + Gram-row dots + residual partials
        float dv[6] = {0,0,0,0,0,0};
        float dself = 0.f;
#pragma unroll
        for (int i = 0; i < 2; i++) {
            const int e = (i*PTPB + tid) * 8;
            const int off = base + e, lo = (e>>9)*PADW + (e&511);
            const short8 fv = *(const short8*)(As + lo);
            const short8 xv = xh[i];
            float gg[8]; short8 gv;
#pragma unroll
            for (int j = 0; j < 8; j++) {
                const float ff = bf2f((unsigned short)fv[j]);
                const float g  = ff - bf2f((unsigned short)xv[j]);
                gg[j] = g; gv[j] = (short)f2bf(g);
                dv[5] = fmaf(ff, ff, dv[5]);
                dself = fmaf(g, g, dself);
            }
            *(short8*)(&g_Fm[idx][off]) = fv;
            *(short8*)(&g_G [idx][off]) = gv;
#pragma unroll
            for (int js = 0; js < MM; js++) {
                if (js != idx && js < nk) {
                    const short8 gj = *(const short8*)(&g_G[js][off]);
#pragma unroll
                    for (int j = 0; j < 8; j++)
                        dv[js] = fmaf(gg[j], bf2f((unsigned short)gj[j]), dv[js]);
                }
            }
        }
        float vals[6];
#pragma unroll
        for (int j = 0; j < MM; j++) vals[j] = (j == idx) ? (dv[j] + dself) : dv[j];
        vals[5] = dv[5];
        red6(vals, redS, &g_acc[it][b][0]);
        GBAR();                                    // g_acc[it] ready device-wide
    }

    // ---------------- final: out = x~last @ weight^T + bias (fp32) -----------
    // As holds F_last; x~last is in xh regs. Restore and GEMM.
#pragma unroll
    for (int i = 0; i < 2; i++) {
        const int e = (i*PTPB + tid) * 8;
        *(short8*)(As + (e>>9)*PADW + (e&511)) = xh[i];
    }
    __syncthreads();
    mfma_ip<1>(g_WbO, bias, As, out + base);

    if (t == 0 && tid == 0)
        astoreu(&g_done, bar_base + (unsigned)nbar);
}

// ===================== fallback multi-launch path (proven) ===================
template<int MODE>
static __device__ __forceinline__ void mfma_gemm(const unsigned short* __restrict__ Wb,
                                                 const float* __restrict__ bvec,
                                                 const unsigned short* AsIn,
                                                 unsigned short* FsOut,
                                                 float* __restrict__ gout)
{
    const int lane = threadIdx.x & 63;
    const int wv   = threadIdx.x >> 6;
    const int lm   = lane & 15;
    const int quad = lane >> 4;
    float4v acc[4][2];
#pragma unroll
    for (int ct = 0; ct < 2; ct++) {
        const float b = bvec[wv*32 + ct*16 + lm];
#pragma unroll
        for (int r16 = 0; r16 < 4; r16++) {
            acc[r16][ct][0]=b; acc[r16][ct][1]=b; acc[r16][ct][2]=b; acc[r16][ct][3]=b;
        }
    }
#pragma unroll
    for (int q = 0; q < 4; q++) {
#pragma unroll
        for (int kb = 0; kb < 4; kb++) {
            const int ko = q*128 + kb*32 + quad*8;
            short8 bf[2];
#pragma unroll
            for (int ct = 0; ct < 2; ct++)
                bf[ct] = *(const short8*)(Wb + (wv*32 + ct*16 + lm)*FD + ko);
            short8 af[4];
#pragma unroll
            for (int r16 = 0; r16 < 4; r16++)
                af[r16] = *(const short8*)(AsIn + (r16*16 + lm)*PADW + ko);
#pragma unroll
            for (int r16 = 0; r16 < 4; r16++) {
                acc[r16][0] = __builtin_amdgcn_mfma_f32_16x16x32_bf16(af[r16], bf[0], acc[r16][0], 0,0,0);
                acc[r16][1] = __builtin_amdgcn_mfma_f32_16x16x32_bf16(af[r16], bf[1], acc[r16][1], 0,0,0);
            }
        }
    }
#pragma unroll
    for (int ct = 0; ct < 2; ct++) {
        const int c = wv*32 + ct*16 + lm;
#pragma unroll
        for (int r16 = 0; r16 < 4; r16++)
#pragma unroll
            for (int r = 0; r < 4; r++) {
                const int row = r16*16 + quad*4 + r;
                if (MODE == 0) FsOut[row*PADW + c] = f2bf(acc[r16][ct][r]);
                else           gout[row*FD + c]    = acc[r16][ct][r];
            }
    }
}

__global__ void __launch_bounds__(256) k_init0(const float* __restrict__ lin_w,
                                               const float* __restrict__ weight)
{
    const int i0 = blockIdx.x*256 + threadIdx.x, stride = gridDim.x*256;
    for (int i = i0; i < FD*FD; i += stride) {
        g_Wb [i] = f2bf(lin_w[i]);
        g_WbO[i] = f2bf(weight[i]);
    }
    float* a = &g_acc[0][0][0];
    for (int i = i0; i < (MAXIT-2)*NBATCH*8; i += stride) a[i] = 0.f;
    float* a0 = &g_acc0[0][0];
    for (int i = i0; i < NBATCH*8; i += stride) a0[i] = 0.f;
}

__global__ void __launch_bounds__(TPB, 4) k_init1(const float* __restrict__ x,
                                                  const float* __restrict__ lin_b)
{
    __shared__ __align__(16) unsigned short As[ROWS*PADW];
    __shared__ __align__(16) unsigned short Fs[ROWS*PADW];
    __shared__ float redS[16][8];
    const int tid = threadIdx.x;
    const int t = blockIdx.x, b = t >> 4;
    const int base = t * (ROWS*FD);

#pragma unroll
    for (int i = 0; i < 4; i++) {
        const int e = (i*TPB + tid) * 8;
        const float4 a0 = *(const float4*)(x + base + e);
        const float4 a1 = *(const float4*)(x + base + e + 4);
        short8 v;
        v[0]=f2bf(a0.x); v[1]=f2bf(a0.y); v[2]=f2bf(a0.z); v[3]=f2bf(a0.w);
        v[4]=f2bf(a1.x); v[5]=f2bf(a1.y); v[6]=f2bf(a1.z); v[7]=f2bf(a1.w);
        *(short8*)(As + (e>>9)*PADW + (e&511)) = v;
    }
    __syncthreads();
    mfma_gemm<0>(g_Wb, lin_b, As, Fs, nullptr);
    __syncthreads();
    float d00 = 0.f;
#pragma unroll
    for (int i = 0; i < 4; i++) {
        const int e = (i*TPB + tid) * 8;
        const int off = base + e, lo = (e>>9)*PADW + (e&511);
        const short8 fv = *(const short8*)(Fs + lo);
        const short8 xv = *(const short8*)(As + lo);
        short8 gv;
#pragma unroll
        for (int j = 0; j < 8; j++) {
            const float g = bf2f((unsigned short)fv[j]) - bf2f((unsigned short)xv[j]);
            gv[j] = (short)f2bf(g);
            d00 = fmaf(g, g, d00);
        }
        *(short8*)(&g_Fm[0][off]) = fv;
        *(short8*)(&g_G [0][off]) = gv;
    }
    __syncthreads();
    mfma_gemm<0>(g_Wb, lin_b, Fs, As, nullptr);
    __syncthreads();
    float d01 = 0.f, d11 = 0.f;
#pragma unroll
    for (int i = 0; i < 4; i++) {
        const int e = (i*TPB + tid) * 8;
        const int off = base + e, lo = (e>>9)*PADW + (e&511);
        const short8 f1 = *(const short8*)(As + lo);
        const short8 f0 = *(const short8*)(Fs + lo);
        const short8 g0 = *(const short8*)(&g_G[0][off]);
        short8 gv;
#pragma unroll
        for (int j = 0; j < 8; j++) {
            const float g = bf2f((unsigned short)f1[j]) - bf2f((unsigned short)f0[j]);
            gv[j] = (short)f2bf(g);
            d11 = fmaf(g, g, d11);
            d01 = fmaf(bf2f((unsigned short)g0[j]), g, d01);
        }
        *(short8*)(&g_Fm[1][off]) = f1;
        *(short8*)(&g_G [1][off]) = gv;
    }
    const float vals[6] = {d00, d01, d11, 0.f, 0.f, 0.f};
    red6(vals, redS, &g_acc0[b][0]);
}

__global__ void __launch_bounds__(TPB, 4) k_iter(const float* __restrict__ lin_b, int k)
{
    __shared__ __align__(16) unsigned short As[ROWS*PADW];
    __shared__ __align__(16) unsigned short Fs[ROWS*PADW];
    __shared__ float gramS[MM][MM];
    __shared__ float alphaS[MM];
    __shared__ float Hs[48];
    __shared__ float redS[16][8];
    __shared__ float sres;

    const int tid = threadIdx.x;
    const int t = blockIdx.x, b = t >> 4;
    const int base = t * (ROWS*FD);
    const int it = k - 2, idx = k % MM, nk = (k < MM) ? k : MM;

    if (k > 2) {
        float v = 0.f;
        if (tid < 32) {
            const int bb = tid & 15;
            const int jj = (tid < 16) ? ((k-1) % MM) : 5;
            v = g_acc[it-1][bb][jj];
        }
        v += __shfl_xor(v, 1); v += __shfl_xor(v, 2);
        v += __shfl_xor(v, 4); v += __shfl_xor(v, 8);
        const float num = __shfl(v, 0), den = __shfl(v, 16);
        if (tid == 0) sres = sqrtf(num) / (1e-5f + sqrtf(den));
    }
    __syncthreads();
    if (k > 2 && sres < TOLV) return;

    if (tid == 0) {
#pragma unroll
        for (int i = 0; i < MM; i++)
#pragma unroll
            for (int j = 0; j < MM; j++) gramS[i][j] = 0.f;
        gramS[0][0] = g_acc0[b][0];
        gramS[0][1] = gramS[1][0] = g_acc0[b][1];
        gramS[1][1] = g_acc0[b][2];
        const int j0 = (k - 5 > 2) ? (k - 5) : 2;
        for (int j = j0; j < k; j++) {
            const int ij = j % MM, nkj = (j < MM) ? j : MM;
            for (int c = 0; c < MM; c++)
                if (c < nkj || c == ij) {
                    const float vv = g_acc[j-2][b][c];
                    gramS[ij][c] = vv; gramS[c][ij] = vv;
                }
        }
        float* H = Hs;
        for (int i = 0; i < 42; i++) H[i] = 0.f;
        for (int j = 0; j < nk; j++) { H[1+j] = 1.f; H[(1+j)*7] = 1.f; }
#pragma unroll
        for (int i = 0; i < MM; i++) H[(1+i)*7 + (1+i)] = LAMV;
        for (int i = 0; i < nk; i++)
            for (int j = 0; j < nk; j++)
                H[(1+i)*7 + (1+j)] = gramS[i][j] + (i == j ? LAMV : 0.f);
        H[6] = 1.f;
        for (int col = 0; col < 6; col++) {
            int p = col; float mx = fabsf(H[col*7+col]);
            for (int r2 = col+1; r2 < 6; r2++) {
                const float vv = fabsf(H[r2*7+col]);
                if (vv > mx) { mx = vv; p = r2; }
            }
            if (p != col)
                for (int j = col; j < 7; j++) { const float tt = H[col*7+j]; H[col*7+j] = H[p*7+j]; H[p*7+j] = tt; }
            const float piv = H[col*7+col];
            for (int r2 = col+1; r2 < 6; r2++) {
                const float fct = H[r2*7+col] / piv;
                for (int j = col+1; j < 7; j++) H[r2*7+j] -= fct * H[col*7+j];
            }
        }
        for (int r2 = 5; r2 >= 0; r2--) {
            float s = H[r2*7+6];
            for (int j = r2+1; j < 6; j++) s -= H[r2*7+j] * H[j*7+6];
            H[r2*7+6] = s / H[r2*7+r2];
        }
#pragma unroll
        for (int m = 0; m < MM; m++) alphaS[m] = H[(1+m)*7+6];
    }
    __syncthreads();

    float al[MM];
#pragma unroll
    for (int m = 0; m < MM; m++) al[m] = alphaS[m];

    if (nk == MM) {
#pragma unroll
        for (int i = 0; i < 4; i++) {
            const int e = (i*TPB + tid) * 8;
            const int off = base + e;
            float s[8] = {0,0,0,0,0,0,0,0};
#pragma unroll
            for (int m = 0; m < MM; m++) {
                const short8 fm = *(const short8*)(&g_Fm[m][off]);
#pragma unroll
                for (int j = 0; j < 8; j++)
                    s[j] = fmaf(al[m], bf2f((unsigned short)fm[j]), s[j]);
            }
            short8 v;
#pragma unroll
            for (int j = 0; j < 8; j++) v[j] = (short)f2bf(s[j]);
            *(short8*)(As + (e>>9)*PADW + (e&511)) = v;
            *(short8*)(&g_xb[off]) = v;
        }
    } else {
#pragma unroll
        for (int i = 0; i < 4; i++) {
            const int e = (i*TPB + tid) * 8;
            const int off = base + e;
            float s[8] = {0,0,0,0,0,0,0,0};
            for (int m = 0; m < nk; m++) {
                const short8 fm = *(const short8*)(&g_Fm[m][off]);
#pragma unroll
                for (int j = 0; j < 8; j++)
                    s[j] = fmaf(al[m], bf2f((unsigned short)fm[j]), s[j]);
            }
            short8 v;
#pragma unroll
            for (int j = 0; j < 8; j++) v[j] = (short)f2bf(s[j]);
            *(short8*)(As + (e>>9)*PADW + (e&511)) = v;
            *(short8*)(&g_xb[off]) = v;
        }
    }
    __syncthreads();
    mfma_gemm<0>(g_Wb, lin_b, As, Fs, nullptr);
    __syncthreads();
    float dv[6] = {0,0,0,0,0,0};
    float dself = 0.f;
#pragma unroll
    for (int i = 0; i < 4; i++) {
        const int e = (i*TPB + tid) * 8;
        const int off = base + e, lo = (e>>9)*PADW + (e&511);
        const short8 fv = *(const short8*)(Fs + lo);
        const short8 xv = *(const short8*)(As + lo);
        float gg[8]; short8 gv;
#pragma unroll
        for (int j = 0; j < 8; j++) {
            const float ff = bf2f((unsigned short)fv[j]);
            const float g  = ff - bf2f((unsigned short)xv[j]);
            gg[j] = g; gv[j] = (short)f2bf(g);
            dv[5] = fmaf(ff, ff, dv[5]);
            dself = fmaf(g, g, dself);
        }
        *(short8*)(&g_Fm[idx][off]) = fv;
        *(short8*)(&g_G [idx][off]) = gv;
#pragma unroll
        for (int js = 0; js < MM; js++) {
            if (js != idx && js < nk) {
                const short8 gj = *(const short8*)(&g_G[js][off]);
#pragma unroll
                for (int j = 0; j < 8; j++)
                    dv[js] = fmaf(gg[j], bf2f((unsigned short)gj[j]), dv[js]);
            }
        }
    }
    float vals[6];
#pragma unroll
    for (int j = 0; j < MM; j++) vals[j] = (j == idx) ? (dv[j] + dself) : dv[j];
    vals[5] = dv[5];
    red6(vals, redS, &g_acc[it][b][0]);
}

__global__ void __launch_bounds__(TPB, 4) k_final(const float* __restrict__ bias,
                                                  float* __restrict__ out)
{
    __shared__ __align__(16) unsigned short As[ROWS*PADW];
    const int tid = threadIdx.x;
    const int base = blockIdx.x * (ROWS*FD);
#pragma unroll
    for (int i = 0; i < 4; i++) {
        const int e = (i*TPB + tid) * 8;
        *(short8*)(As + (e>>9)*PADW + (e&511)) = *(const short8*)(&g_xb[base + e]);
    }
    __syncthreads();
    mfma_gemm<1>(g_WbO, bias, As, nullptr, out + base);
}

extern "C" void kernel_launch(void* const* d_in, const int* in_sizes, int n_in,
                              void* d_out, int out_size, void* d_ws, size_t ws_size,
                              hipStream_t stream)
{
    (void)in_sizes; (void)n_in; (void)out_size; (void)d_ws; (void)ws_size;
    const float* x      = (const float*)d_in[0];
    const float* lin_w  = (const float*)d_in[1];
    const float* lin_b  = (const float*)d_in[2];
    const float* weight = (const float*)d_in[3];
    const float* bias   = (const float*)d_in[4];
    float* out = (float*)d_out;

    void* args[] = {(void*)&x, (void*)&lin_w, (void*)&lin_b,
                    (void*)&weight, (void*)&bias, (void*)&out};
    if (hipLaunchCooperativeKernel(reinterpret_cast<const void*>(&k_anderson),
                                   dim3(PNBLK), dim3(PTPB), args, 0, stream) != hipSuccess) {
        // fallback: proven multi-launch path
        hipLaunchKernelGGL(k_init0, dim3(512),  dim3(256), 0, stream, lin_w, weight);
        hipLaunchKernelGGL(k_init1, dim3(NBLK), dim3(TPB), 0, stream, x, lin_b);
        for (int k = 2; k < MAXIT; k++)
            hipLaunchKernelGGL(k_iter, dim3(NBLK), dim3(TPB), 0, stream, lin_b, k);
        hipLaunchKernelGGL(k_final, dim3(NBLK), dim3(TPB), 0, stream, bias, out);
    }
}

// Round 4
// 992.600 us; speedup vs baseline: 1.3318x; 1.3318x over previous
//
#include <hip/hip_runtime.h>
#include <math.h>

#define FD     512
#define NBATCH 16
#define NROWS  16384
#define ROWS   64              // rows per block
#define NBLK   (NROWS/ROWS)    // 256 blocks = 1 per CU
#define TPB    1024            // 16 waves/block
#define MM     5
#define LAMV   1e-4f
#define MAXIT  50
#define TOLV   0.01f
#define NTOT   8388608
#define PADW   520             // LDS row stride (bf16 elems), 16B aligned

typedef __attribute__((ext_vector_type(8))) short  short8;   // 8 bf16
typedef __attribute__((ext_vector_type(4))) float  float4v;  // MFMA C/D frag

// Persistent device state; fully rewritten (or provably unused) every call.
__device__ unsigned short g_Fm[MM][NTOT];
__device__ unsigned short g_G [MM][NTOT];
__device__ unsigned short g_xb[NTOT];          // fallback path only
__device__ unsigned short g_Wb [FD*FD];        // bf16(lin_w) row-major
__device__ unsigned short g_WbO[FD*FD];        // bf16(weight) row-major
__device__ float g_acc [MAXIT-2][NBATCH][8];   // fallback path only
__device__ float g_acc0[NBATCH][8];            // fallback path only

// Persistent-path sync state. ALL cross-block data flows through these, all
// accessed ONLY with agent-scope atomics, all MONOTONIC counters (g_done
// carries the base across stream-ordered launches). Layout rule: one cache
// line per writer (g_part[t], g_arrive line-shared by 16 blocks is fine for
// stores), one line per batch for release+alphas (<=16 spinners/line).
__device__ float    g_part[NBLK][16];          // per-block partial dots [0..5]
__device__ unsigned g_arrive[NBLK];            // per-block arrival counter
__device__ unsigned g_rel[NBATCH][16];         // [0]=(counter<<1)|stop, [1..5]=alpha bits
__device__ unsigned g_done;                    // final counter of previous launch

static __device__ __forceinline__ unsigned short f2bf(float f) {
    unsigned u = __float_as_uint(f);
    u += 0x7fff + ((u >> 16) & 1);             // RNE
    return (unsigned short)(u >> 16);
}
static __device__ __forceinline__ float bf2f(unsigned short s) {
    return __uint_as_float(((unsigned)s) << 16);
}
static __device__ __forceinline__ float aloadf(const float* p) {
    return __hip_atomic_load(p, __ATOMIC_RELAXED, __HIP_MEMORY_SCOPE_AGENT);
}
static __device__ __forceinline__ unsigned aloadu(const unsigned* p) {
    return __hip_atomic_load(p, __ATOMIC_RELAXED, __HIP_MEMORY_SCOPE_AGENT);
}
static __device__ __forceinline__ void astoref(float* p, float v) {
    __hip_atomic_store(p, v, __ATOMIC_RELAXED, __HIP_MEMORY_SCOPE_AGENT);
}
static __device__ __forceinline__ void astoreu(unsigned* p, unsigned v) {
    __hip_atomic_store(p, v, __ATOMIC_RELAXED, __HIP_MEMORY_SCOPE_AGENT);
}

// ---------- 64x512 tile GEMM, IN-PLACE on As: D = A @ W^T + bias -------------
// 16 waves; wave owns 32 cols (2 ct) x 64 rows (4 r16). Accumulator stays in
// regs until all A-frag LDS reads complete (barrier), then C overwrites As.
// MODE 0: bf16 -> As (in-place). MODE 1: fp32 -> gout (no LDS hazard).
template<int MODE>
static __device__ __forceinline__ void mfma_ip(const unsigned short* __restrict__ Wb,
                                               const float* __restrict__ bvec,
                                               unsigned short* As,
                                               float* __restrict__ gout)
{
    const int lane = threadIdx.x & 63;
    const int wv   = threadIdx.x >> 6;     // 0..15
    const int lm   = lane & 15;
    const int quad = lane >> 4;
    float4v acc[4][2];
#pragma unroll
    for (int ct = 0; ct < 2; ct++) {
        const float b = bvec[wv*32 + ct*16 + lm];
#pragma unroll
        for (int r16 = 0; r16 < 4; r16++) {
            acc[r16][ct][0]=b; acc[r16][ct][1]=b; acc[r16][ct][2]=b; acc[r16][ct][3]=b;
        }
    }
#pragma unroll
    for (int q = 0; q < 4; q++) {
#pragma unroll
        for (int kb = 0; kb < 4; kb++) {
            const int ko = q*128 + kb*32 + quad*8;
            short8 bf[2];
#pragma unroll
            for (int ct = 0; ct < 2; ct++)
                bf[ct] = *(const short8*)(Wb + (wv*32 + ct*16 + lm)*FD + ko);
            short8 af[4];
#pragma unroll
            for (int r16 = 0; r16 < 4; r16++)
                af[r16] = *(const short8*)(As + (r16*16 + lm)*PADW + ko);
#pragma unroll
            for (int r16 = 0; r16 < 4; r16++) {
                acc[r16][0] = __builtin_amdgcn_mfma_f32_16x16x32_bf16(af[r16], bf[0], acc[r16][0], 0,0,0);
                acc[r16][1] = __builtin_amdgcn_mfma_f32_16x16x32_bf16(af[r16], bf[1], acc[r16][1], 0,0,0);
            }
        }
    }
    if (MODE == 0) __syncthreads();        // all A-reads done before overwrite
#pragma unroll
    for (int ct = 0; ct < 2; ct++) {
        const int c = wv*32 + ct*16 + lm;
#pragma unroll
        for (int r16 = 0; r16 < 4; r16++)
#pragma unroll
            for (int r = 0; r < 4; r++) {
                const int row = r16*16 + quad*4 + r;
                if (MODE == 0) As[row*PADW + c] = f2bf(acc[r16][ct][r]);
                else           gout[row*FD + c] = acc[r16][ct][r];
            }
    }
    if (MODE == 0) __syncthreads();        // C visible to all waves
}

// Block-internal reduce of 6 partials -> this block's OWN g_part line.
static __device__ __forceinline__ void red6p(const float vals[6], float (*redS)[8], int t)
{
    const int lane = threadIdx.x & 63, wv = threadIdx.x >> 6;
#pragma unroll
    for (int j = 0; j < 6; j++) {
        float v = vals[j];
#pragma unroll
        for (int o = 32; o; o >>= 1) v += __shfl_down(v, o);
        if (lane == 0) redS[wv][j] = v;
    }
    __syncthreads();
    if (threadIdx.x < 6) {
        float s = 0.f;
#pragma unroll
        for (int w = 0; w < 16; w++) s += redS[w][threadIdx.x];
        astoref(&g_part[t][threadIdx.x], s);   // uncontended: own line
    }
}

// Master: wait until all 256 blocks arrived at counter c (wave 0 of block 0).
static __device__ __forceinline__ void master_wait(int lane, unsigned c)
{
    for (;;) {
        int ok = ((int)(aloadu(&g_arrive[lane      ]) - c) >= 0)
               & ((int)(aloadu(&g_arrive[lane +  64]) - c) >= 0)
               & ((int)(aloadu(&g_arrive[lane + 128]) - c) >= 0)
               & ((int)(aloadu(&g_arrive[lane + 192]) - c) >= 0);
        if (__all(ok)) break;
        __builtin_amdgcn_s_sleep(2);
    }
}

// Bordered (M+1)x(M+1) solve, 6x7 augmented GE with bubble partial-pivoting,
// fully static-indexed registers (identical H build + elimination arithmetic
// to the proven serial solver; bubble-swap selects the same max pivot).
static __device__ __forceinline__ void build_solve(const float* g25, int nk1, float* alpha5)
{
    float H[42];
#pragma unroll
    for (int i = 0; i < 42; i++) H[i] = 0.f;
    H[6] = 1.f;                                // rhs = e0
#pragma unroll
    for (int j = 0; j < 5; j++) {
        const float mj = (j < nk1) ? 1.f : 0.f;
        H[1+j] = mj; H[(1+j)*7] = mj;
    }
#pragma unroll
    for (int i = 0; i < 5; i++)
#pragma unroll
        for (int j = 0; j < 5; j++)
            H[(1+i)*7 + (1+j)] = g25[i*5+j] + ((i == j) ? LAMV : 0.f);
#pragma unroll
    for (int col = 0; col < 6; col++) {
#pragma unroll
        for (int r = 0; r < 6; r++) if (r > col) {
            const bool sw = fabsf(H[r*7+col]) > fabsf(H[col*7+col]);
#pragma unroll
            for (int j = 0; j < 7; j++) if (j >= col) {
                const float a = H[col*7+j], c2 = H[r*7+j];
                H[col*7+j] = sw ? c2 : a; H[r*7+j] = sw ? a : c2;
            }
        }
        const float piv = H[col*7+col];
#pragma unroll
        for (int r = 0; r < 6; r++) if (r > col) {
            const float fct = H[r*7+col] / piv;
#pragma unroll
            for (int j = 0; j < 7; j++) if (j > col) H[r*7+j] -= fct * H[col*7+j];
        }
    }
#pragma unroll
    for (int r = 5; r >= 0; r--) {
        float s = H[r*7+6];
#pragma unroll
        for (int j = 0; j < 6; j++) if (j > r) s -= H[r*7+j] * H[j*7+6];
        H[r*7+6] = s / H[r*7+r];
    }
#pragma unroll
    for (int m = 0; m < 5; m++) alpha5[m] = H[(1+m)*7+6];
}

// ======================= persistent cooperative kernel =======================
__global__ void __launch_bounds__(TPB, 4) k_anderson(
    const float* __restrict__ x,     const float* __restrict__ lin_w,
    const float* __restrict__ lin_b, const float* __restrict__ weight,
    const float* __restrict__ bias,  float* __restrict__ out)
{
    __shared__ __align__(16) unsigned short As[ROWS*PADW];   // F / x~ tile
    __shared__ __align__(16) unsigned short Gs[ROWS*PADW];   // newest G tile
    __shared__ float redS[16][8];
    __shared__ float alphaS[MM];
    __shared__ int   stopS;
    __shared__ unsigned baseSh;
    // master-only (block 0 wave 0)
    __shared__ float m_rowS[16][6];
    __shared__ float gram16[16][25];

    const int tid  = threadIdx.x;
    const int lane = tid & 63, wv = tid >> 6;
    const int t    = blockIdx.x, b = t >> 4;
    const int base = t * (ROWS*FD);

    if (tid == 0) baseSh = aloadu(&g_done);

    // ---------- phase 0: weights -> bf16 (coherent stores), x -> As + regs ----
    if (tid < 512) {                            // 256 blk x 512 = FD*FD/2 pairs
        const int wi = t*512 + tid;
        const float2 w0 = *(const float2*)(lin_w  + 2*wi);
        const float2 w1 = *(const float2*)(weight + 2*wi);
        astoreu((unsigned*)g_Wb  + wi, (unsigned)f2bf(w0.x) | ((unsigned)f2bf(w0.y) << 16));
        astoreu((unsigned*)g_WbO + wi, (unsigned)f2bf(w1.x) | ((unsigned)f2bf(w1.y) << 16));
    }
    short8 xh[4];                               // this thread's 32 bf16 of x~
#pragma unroll
    for (int i = 0; i < 4; i++) {
        const int e = (i*TPB + tid) * 8;
        const float4 a0 = *(const float4*)(x + base + e);
        const float4 a1 = *(const float4*)(x + base + e + 4);
        short8 v;
        v[0]=f2bf(a0.x); v[1]=f2bf(a0.y); v[2]=f2bf(a0.z); v[3]=f2bf(a0.w);
        v[4]=f2bf(a1.x); v[5]=f2bf(a1.y); v[6]=f2bf(a1.z); v[7]=f2bf(a1.w);
        xh[i] = v;
        *(short8*)(As + (e>>9)*PADW + (e&511)) = v;
    }
    __syncthreads();                            // drains weight stores; baseSh visible
    const unsigned bb0 = baseSh;
    if (tid == 0) astoreu(&g_arrive[t], bb0 + 1);
    if (t == 0 && wv == 0) {                    // master: barrier 1 (weights ready)
        master_wait(lane, bb0 + 1);
        if (lane < 16) {
#pragma unroll
            for (int i = 0; i < 25; i++) gram16[lane][i] = 0.f;
        }
        asm volatile("s_waitcnt lgkmcnt(0)" ::: "memory");
        if (lane < 16) astoreu(&g_rel[lane][0], (bb0 + 1) << 1);
    }
    if (tid == 0) {
        const unsigned tgt = (bb0 + 1) << 1;
        unsigned rw;
        while ((int)((rw = aloadu(&g_rel[b][0])) - tgt) < 0) __builtin_amdgcn_s_sleep(4);
    }
    __syncthreads();

    // ---------- init: F0=f(x~0), F1=f(F~0), G0, G1, init Gram dots ------------
    mfma_ip<0>(g_Wb, lin_b, As, nullptr);       // As = bf16(F0)
    float d00 = 0.f;
    short8 fh[4];                               // F0 (for G1 = F1 - F0)
#pragma unroll
    for (int i = 0; i < 4; i++) {
        const int e = (i*TPB + tid) * 8;
        const int off = base + e, lo = (e>>9)*PADW + (e&511);
        const short8 fv = *(const short8*)(As + lo);
        const short8 xv = xh[i];
        short8 gv;
#pragma unroll
        for (int j = 0; j < 8; j++) {
            const float g = bf2f((unsigned short)fv[j]) - bf2f((unsigned short)xv[j]);
            gv[j] = (short)f2bf(g);
            d00 = fmaf(g, g, d00);
        }
        *(short8*)(&g_Fm[0][off]) = fv;
        *(short8*)(&g_G [0][off]) = gv;
        fh[i] = fv;
    }
    mfma_ip<0>(g_Wb, lin_b, As, nullptr);       // As = bf16(F1)
    float d01 = 0.f, d11 = 0.f;
#pragma unroll
    for (int i = 0; i < 4; i++) {
        const int e = (i*TPB + tid) * 8;
        const int off = base + e, lo = (e>>9)*PADW + (e&511);
        const short8 f1 = *(const short8*)(As + lo);
        const short8 f0 = fh[i];
        const short8 xv = xh[i];
        short8 gv;
#pragma unroll
        for (int j = 0; j < 8; j++) {
            const float g = bf2f((unsigned short)f1[j]) - bf2f((unsigned short)f0[j]);
            gv[j] = (short)f2bf(g);
            d11 = fmaf(g, g, d11);
            // recompute bf16(G0) from fh/xh: bit-identical to the stored value
            const float g0 = bf2f(f2bf(bf2f((unsigned short)f0[j]) - bf2f((unsigned short)xv[j])));
            d01 = fmaf(g0, g, d01);
        }
        *(short8*)(&g_Fm[1][off]) = f1;
        *(short8*)(&g_G [1][off]) = gv;
        *(short8*)(Gs + lo) = gv;               // Gs = newest G (G1)
    }
    {
        const float vals[6] = {d00, d01, d11, 0.f, 0.f, 0.f};
        red6p(vals, redS, t);
    }
    asm volatile("s_waitcnt vmcnt(0)" ::: "memory");
    if (tid == 0) astoreu(&g_arrive[t], bb0 + 2);
    if (t == 0 && wv == 0) {                    // master: barrier 2 (init dots)
        master_wait(lane, bb0 + 2);
        if (lane < 48) {                        // gather 16 batches x 3 dots
            const int b1 = lane / 3, d1 = lane % 3;
            float v = 0.f;
            for (int i = 0; i < 16; i++) v += aloadf(&g_part[b1*16 + i][d1]);
            m_rowS[b1][d1] = v;
        }
        asm volatile("s_waitcnt lgkmcnt(0)" ::: "memory");
        __builtin_amdgcn_sched_barrier(0);
        if (lane < 16) {
            gram16[lane][0*5+0] = m_rowS[lane][0];
            gram16[lane][0*5+1] = m_rowS[lane][1];
            gram16[lane][1*5+0] = m_rowS[lane][1];
            gram16[lane][1*5+1] = m_rowS[lane][2];
            float al5[5];
            build_solve(gram16[lane], 2, al5);  // alphas for k=2
#pragma unroll
            for (int m = 0; m < 5; m++) astoreu(&g_rel[lane][1+m], __float_as_uint(al5[m]));
        }
        asm volatile("s_waitcnt vmcnt(0)" ::: "memory");
        if (lane < 16) astoreu(&g_rel[lane][0], (bb0 + 2) << 1);
    }

    // ---------------- Anderson iterations (k = 2..49) -------------------------
    for (int k = 2; ; k++) {
        const int idx = k % MM, nk = (k < MM) ? k : MM;
        const int sF  = (k == 2) ? 1 : ((k - 1) % MM);  // slot held in As AND Gs

        // prefetch pass-1 global reads, chunks 0-1 (depend only on this block's
        // own prior writes, so they are safe to issue before the release poll)
        short8 pf0[5], pf1[5];
#pragma unroll
        for (int m = 0; m < 5; m++) if (m != sF && m < nk) {
            pf0[m] = *(const short8*)(&g_Fm[m][base + (0*TPB + tid)*8]);
            pf1[m] = *(const short8*)(&g_Fm[m][base + (1*TPB + tid)*8]);
        }
        __builtin_amdgcn_sched_barrier(0);

        if (tid == 0) {                         // poll release for iteration k
            const unsigned tgt = (bb0 + (unsigned)k) << 1;
            unsigned rw;
            while ((int)((rw = aloadu(&g_rel[b][0])) - tgt) < 0) __builtin_amdgcn_s_sleep(4);
            stopS = (int)(rw & 1u);
            if (!(rw & 1u)) {
#pragma unroll
                for (int j = 0; j < 5; j++)
                    alphaS[j] = __uint_as_float(aloadu(&g_rel[b][1+j]));
            }
        }
        __syncthreads();
        if (stopS) break;                       // uniform; xh = x~ of iter k-1

        float al[5];
#pragma unroll
        for (int m = 0; m < 5; m++) al[m] = alphaS[m];

        // --- pass 1: x~ = bf16(sum alpha_m Fm[m]) -> As (in place) + xh regs
#pragma unroll
        for (int i = 0; i < 4; i++) {
            const int e = (i*TPB + tid) * 8;
            const int off = base + e, lo = (e>>9)*PADW + (e&511);
            const short8 asv = *(const short8*)(As + lo);
            float s[8] = {0,0,0,0,0,0,0,0};
#pragma unroll
            for (int m = 0; m < 5; m++) if (m < nk) {
                short8 fm;
                if (m == sF)      fm = asv;
                else if (i == 0)  fm = pf0[m];
                else if (i == 1)  fm = pf1[m];
                else              fm = *(const short8*)(&g_Fm[m][off]);
#pragma unroll
                for (int j = 0; j < 8; j++)
                    s[j] = fmaf(al[m], bf2f((unsigned short)fm[j]), s[j]);
            }
            short8 v;
#pragma unroll
            for (int j = 0; j < 8; j++) v[j] = (short)f2bf(s[j]);
            xh[i] = v;
            *(short8*)(As + lo) = v;
        }
        __syncthreads();
        // --- pass 2: As = bf16(x~ @ lin_w^T + lin_b)  (in-place)
        mfma_ip<0>(g_Wb, lin_b, As, nullptr);
        // --- pass 3: state writes + Gram-row dots + residual partials
        float dv[6] = {0,0,0,0,0,0};
        float dself = 0.f;
#pragma unroll
        for (int i = 0; i < 4; i++) {
            const int e = (i*TPB + tid) * 8;
            const int off = base + e, lo = (e>>9)*PADW + (e&511);
            const short8 fv  = *(const short8*)(As + lo);
            const short8 gsv = *(const short8*)(Gs + lo);   // old G[sF]
            const short8 xv  = xh[i];
            float gg[8]; short8 gv;
#pragma unroll
            for (int j = 0; j < 8; j++) {
                const float ff = bf2f((unsigned short)fv[j]);
                const float g  = ff - bf2f((unsigned short)xv[j]);
                gg[j] = g; gv[j] = (short)f2bf(g);
                dv[5] = fmaf(ff, ff, dv[5]);
                dself = fmaf(g, g, dself);
            }
            *(short8*)(&g_Fm[idx][off]) = fv;
            *(short8*)(&g_G [idx][off]) = gv;
#pragma unroll
            for (int js = 0; js < 5; js++) if (js != idx && js < nk) {
                if (js == sF) {
#pragma unroll
                    for (int j = 0; j < 8; j++)
                        dv[js] = fmaf(gg[j], bf2f((unsigned short)gsv[j]), dv[js]);
                } else {
                    const short8 gj = *(const short8*)(&g_G[js][off]);
#pragma unroll
                    for (int j = 0; j < 8; j++)
                        dv[js] = fmaf(gg[j], bf2f((unsigned short)gj[j]), dv[js]);
                }
            }
            *(short8*)(Gs + lo) = gv;           // Gs = newest G
        }
        float vals[6];
#pragma unroll
        for (int j = 0; j < 5; j++) vals[j] = (j == idx) ? (dv[j] + dself) : dv[j];
        vals[5] = dv[5];
        red6p(vals, redS, t);
        asm volatile("s_waitcnt vmcnt(0)" ::: "memory");
        if (tid == 0) astoreu(&g_arrive[t], bb0 + (unsigned)k + 1);

        // master: process iteration k's dots, gate iteration k+1
        if (t == 0 && wv == 0) {
            const unsigned c = bb0 + (unsigned)k + 1;
            master_wait(lane, c);
            {                                   // gather 16 batches x 6 dots
                const int p1 = lane, b1 = p1/6, d1 = p1%6;
                float v1 = 0.f, v2 = 0.f;
                const int p2 = lane + 64, b2 = p2/6, d2 = p2%6;
                const bool h2 = (lane < 32);
                for (int i = 0; i < 16; i++) {
                    v1 += aloadf(&g_part[b1*16 + i][d1]);
                    if (h2) v2 += aloadf(&g_part[b2*16 + i][d2]);
                }
                m_rowS[b1][d1] = v1;
                if (h2) m_rowS[b2][d2] = v2;
            }
            asm volatile("s_waitcnt lgkmcnt(0)" ::: "memory");
            __builtin_amdgcn_sched_barrier(0);
            if (lane < 16) {                    // incremental Gram row (== replay)
#pragma unroll
                for (int c2 = 0; c2 < 5; c2++) if (c2 < nk || c2 == idx) {
                    const float vv = m_rowS[lane][c2];
                    gram16[lane][idx*5 + c2] = vv;
                    gram16[lane][c2*5 + idx] = vv;
                }
            }
            float nb = (lane < 16) ? m_rowS[lane][idx] : 0.f;
            float db = (lane < 16) ? m_rowS[lane][5]   : 0.f;
#pragma unroll
            for (int o = 1; o < 64; o <<= 1) { nb += __shfl_xor(nb, o); db += __shfl_xor(db, o); }
            const float res = sqrtf(nb) / (1e-5f + sqrtf(db));
            const int stop = (res < TOLV) || (k + 1 >= MAXIT);
            asm volatile("s_waitcnt lgkmcnt(0)" ::: "memory");
            if (!stop) {
                if (lane < 16) {
                    const int nk1 = (k + 1 < MM) ? (k + 1) : MM;
                    float al5[5];
                    build_solve(gram16[lane], nk1, al5);
#pragma unroll
                    for (int m = 0; m < 5; m++)
                        astoreu(&g_rel[lane][1+m], __float_as_uint(al5[m]));
                }
                asm volatile("s_waitcnt vmcnt(0)" ::: "memory");
                if (lane < 16) astoreu(&g_rel[lane][0], c << 1);
            } else {
                if (lane < 16) astoreu(&g_rel[lane][0], (c << 1) | 1u);
                if (lane == 0) astoreu(&g_done, c);
            }
        }
    }

    // ---------------- final: out = x~last @ weight^T + bias (fp32) -----------
#pragma unroll
    for (int i = 0; i < 4; i++) {
        const int e = (i*TPB + tid) * 8;
        *(short8*)(As + (e>>9)*PADW + (e&511)) = xh[i];
    }
    __syncthreads();
    mfma_ip<1>(g_WbO, bias, As, out + base);
}

// ===================== fallback multi-launch path (proven) ===================
template<int MODE>
static __device__ __forceinline__ void mfma_gemm(const unsigned short* __restrict__ Wb,
                                                 const float* __restrict__ bvec,
                                                 const unsigned short* AsIn,
                                                 unsigned short* FsOut,
                                                 float* __restrict__ gout)
{
    const int lane = threadIdx.x & 63;
    const int wv   = threadIdx.x >> 6;
    const int lm   = lane & 15;
    const int quad = lane >> 4;
    float4v acc[4][2];
#pragma unroll
    for (int ct = 0; ct < 2; ct++) {
        const float b = bvec[wv*32 + ct*16 + lm];
#pragma unroll
        for (int r16 = 0; r16 < 4; r16++) {
            acc[r16][ct][0]=b; acc[r16][ct][1]=b; acc[r16][ct][2]=b; acc[r16][ct][3]=b;
        }
    }
#pragma unroll
    for (int q = 0; q < 4; q++) {
#pragma unroll
        for (int kb = 0; kb < 4; kb++) {
            const int ko = q*128 + kb*32 + quad*8;
            short8 bf[2];
#pragma unroll
            for (int ct = 0; ct < 2; ct++)
                bf[ct] = *(const short8*)(Wb + (wv*32 + ct*16 + lm)*FD + ko);
            short8 af[4];
#pragma unroll
            for (int r16 = 0; r16 < 4; r16++)
                af[r16] = *(const short8*)(AsIn + (r16*16 + lm)*PADW + ko);
#pragma unroll
            for (int r16 = 0; r16 < 4; r16++) {
                acc[r16][0] = __builtin_amdgcn_mfma_f32_16x16x32_bf16(af[r16], bf[0], acc[r16][0], 0,0,0);
                acc[r16][1] = __builtin_amdgcn_mfma_f32_16x16x32_bf16(af[r16], bf[1], acc[r16][1], 0,0,0);
            }
        }
    }
#pragma unroll
    for (int ct = 0; ct < 2; ct++) {
        const int c = wv*32 + ct*16 + lm;
#pragma unroll
        for (int r16 = 0; r16 < 4; r16++)
#pragma unroll
            for (int r = 0; r < 4; r++) {
                const int row = r16*16 + quad*4 + r;
                if (MODE == 0) FsOut[row*PADW + c] = f2bf(acc[r16][ct][r]);
                else           gout[row*FD + c]    = acc[r16][ct][r];
            }
    }
}

static __device__ __forceinline__ void red6(const float vals[6], float (*redS)[8], float* accrow)
{
    const int lane = threadIdx.x & 63, wv = threadIdx.x >> 6;
#pragma unroll
    for (int j = 0; j < 6; j++) {
        float v = vals[j];
#pragma unroll
        for (int o = 32; o; o >>= 1) v += __shfl_down(v, o);
        if (lane == 0) redS[wv][j] = v;
    }
    __syncthreads();
    if (threadIdx.x < 6) {
        float s = 0.f;
#pragma unroll
        for (int w = 0; w < 16; w++) s += redS[w][threadIdx.x];
        atomicAdd(accrow + threadIdx.x, s);
    }
}

__global__ void __launch_bounds__(256) k_init0(const float* __restrict__ lin_w,
                                               const float* __restrict__ weight)
{
    const int i0 = blockIdx.x*256 + threadIdx.x, stride = gridDim.x*256;
    for (int i = i0; i < FD*FD; i += stride) {
        g_Wb [i] = f2bf(lin_w[i]);
        g_WbO[i] = f2bf(weight[i]);
    }
    float* a = &g_acc[0][0][0];
    for (int i = i0; i < (MAXIT-2)*NBATCH*8; i += stride) a[i] = 0.f;
    float* a0 = &g_acc0[0][0];
    for (int i = i0; i < NBATCH*8; i += stride) a0[i] = 0.f;
}

__global__ void __launch_bounds__(TPB, 4) k_init1(const float* __restrict__ x,
                                                  const float* __restrict__ lin_b)
{
    __shared__ __align__(16) unsigned short As[ROWS*PADW];
    __shared__ __align__(16) unsigned short Fs[ROWS*PADW];
    __shared__ float redS[16][8];
    const int tid = threadIdx.x;
    const int t = blockIdx.x, b = t >> 4;
    const int base = t * (ROWS*FD);

#pragma unroll
    for (int i = 0; i < 4; i++) {
        const int e = (i*TPB + tid) * 8;
        const float4 a0 = *(const float4*)(x + base + e);
        const float4 a1 = *(const float4*)(x + base + e + 4);
        short8 v;
        v[0]=f2bf(a0.x); v[1]=f2bf(a0.y); v[2]=f2bf(a0.z); v[3]=f2bf(a0.w);
        v[4]=f2bf(a1.x); v[5]=f2bf(a1.y); v[6]=f2bf(a1.z); v[7]=f2bf(a1.w);
        *(short8*)(As + (e>>9)*PADW + (e&511)) = v;
    }
    __syncthreads();
    mfma_gemm<0>(g_Wb, lin_b, As, Fs, nullptr);
    __syncthreads();
    float d00 = 0.f;
#pragma unroll
    for (int i = 0; i < 4; i++) {
        const int e = (i*TPB + tid) * 8;
        const int off = base + e, lo = (e>>9)*PADW + (e&511);
        const short8 fv = *(const short8*)(Fs + lo);
        const short8 xv = *(const short8*)(As + lo);
        short8 gv;
#pragma unroll
        for (int j = 0; j < 8; j++) {
            const float g = bf2f((unsigned short)fv[j]) - bf2f((unsigned short)xv[j]);
            gv[j] = (short)f2bf(g);
            d00 = fmaf(g, g, d00);
        }
        *(short8*)(&g_Fm[0][off]) = fv;
        *(short8*)(&g_G [0][off]) = gv;
    }
    __syncthreads();
    mfma_gemm<0>(g_Wb, lin_b, Fs, As, nullptr);
    __syncthreads();
    float d01 = 0.f, d11 = 0.f;
#pragma unroll
    for (int i = 0; i < 4; i++) {
        const int e = (i*TPB + tid) * 8;
        const int off = base + e, lo = (e>>9)*PADW + (e&511);
        const short8 f1 = *(const short8*)(As + lo);
        const short8 f0 = *(const short8*)(Fs + lo);
        const short8 g0 = *(const short8*)(&g_G[0][off]);
        short8 gv;
#pragma unroll
        for (int j = 0; j < 8; j++) {
            const float g = bf2f((unsigned short)f1[j]) - bf2f((unsigned short)f0[j]);
            gv[j] = (short)f2bf(g);
            d11 = fmaf(g, g, d11);
            d01 = fmaf(bf2f((unsigned short)g0[j]), g, d01);
        }
        *(short8*)(&g_Fm[1][off]) = f1;
        *(short8*)(&g_G [1][off]) = gv;
    }
    const float vals[6] = {d00, d01, d11, 0.f, 0.f, 0.f};
    red6(vals, redS, &g_acc0[b][0]);
}

__global__ void __launch_bounds__(TPB, 4) k_iter(const float* __restrict__ lin_b, int k)
{
    __shared__ __align__(16) unsigned short As[ROWS*PADW];
    __shared__ __align__(16) unsigned short Fs[ROWS*PADW];
    __shared__ float gramS[MM][MM];
    __shared__ float alphaS[MM];
    __shared__ float Hs[48];
    __shared__ float redS[16][8];
    __shared__ float sres;

    const int tid = threadIdx.x;
    const int t = blockIdx.x, b = t >> 4;
    const int base = t * (ROWS*FD);
    const int it = k - 2, idx = k % MM, nk = (k < MM) ? k : MM;

    if (k > 2) {
        float v = 0.f;
        if (tid < 32) {
            const int bb = tid & 15;
            const int jj = (tid < 16) ? ((k-1) % MM) : 5;
            v = g_acc[it-1][bb][jj];
        }
        v += __shfl_xor(v, 1); v += __shfl_xor(v, 2);
        v += __shfl_xor(v, 4); v += __shfl_xor(v, 8);
        const float num = __shfl(v, 0), den = __shfl(v, 16);
        if (tid == 0) sres = sqrtf(num) / (1e-5f + sqrtf(den));
    }
    __syncthreads();
    if (k > 2 && sres < TOLV) return;

    if (tid == 0) {
#pragma unroll
        for (int i = 0; i < MM; i++)
#pragma unroll
            for (int j = 0; j < MM; j++) gramS[i][j] = 0.f;
        gramS[0][0] = g_acc0[b][0];
        gramS[0][1] = gramS[1][0] = g_acc0[b][1];
        gramS[1][1] = g_acc0[b][2];
        const int j0 = (k - 5 > 2) ? (k - 5) : 2;
        for (int j = j0; j < k; j++) {
            const int ij = j % MM, nkj = (j < MM) ? j : MM;
            for (int c = 0; c < MM; c++)
                if (c < nkj || c == ij) {
                    const float vv = g_acc[j-2][b][c];
                    gramS[ij][c] = vv; gramS[c][ij] = vv;
                }
        }
        float* H = Hs;
        for (int i = 0; i < 42; i++) H[i] = 0.f;
        for (int j = 0; j < nk; j++) { H[1+j] = 1.f; H[(1+j)*7] = 1.f; }
#pragma unroll
        for (int i = 0; i < MM; i++) H[(1+i)*7 + (1+i)] = LAMV;
        for (int i = 0; i < nk; i++)
            for (int j = 0; j < nk; j++)
                H[(1+i)*7 + (1+j)] = gramS[i][j] + (i == j ? LAMV : 0.f);
        H[6] = 1.f;
        for (int col = 0; col < 6; col++) {
            int p = col; float mx = fabsf(H[col*7+col]);
            for (int r2 = col+1; r2 < 6; r2++) {
                const float vv = fabsf(H[r2*7+col]);
                if (vv > mx) { mx = vv; p = r2; }
            }
            if (p != col)
                for (int j = col; j < 7; j++) { const float tt = H[col*7+j]; H[col*7+j] = H[p*7+j]; H[p*7+j] = tt; }
            const float piv = H[col*7+col];
            for (int r2 = col+1; r2 < 6; r2++) {
                const float fct = H[r2*7+col] / piv;
                for (int j = col+1; j < 7; j++) H[r2*7+j] -= fct * H[col*7+j];
            }
        }
        for (int r2 = 5; r2 >= 0; r2--) {
            float s = H[r2*7+6];
            for (int j = r2+1; j < 6; j++) s -= H[r2*7+j] * H[j*7+6];
            H[r2*7+6] = s / H[r2*7+r2];
        }
#pragma unroll
        for (int m = 0; m < MM; m++) alphaS[m] = H[(1+m)*7+6];
    }
    __syncthreads();

    float al[MM];
#pragma unroll
    for (int m = 0; m < MM; m++) al[m] = alphaS[m];

    if (nk == MM) {
#pragma unroll
        for (int i = 0; i < 4; i++) {
            const int e = (i*TPB + tid) * 8;
            const int off = base + e;
            float s[8] = {0,0,0,0,0,0,0,0};
#pragma unroll
            for (int m = 0; m < MM; m++) {
                const short8 fm = *(const short8*)(&g_Fm[m][off]);
#pragma unroll
                for (int j = 0; j < 8; j++)
                    s[j] = fmaf(al[m], bf2f((unsigned short)fm[j]), s[j]);
            }
            short8 v;
#pragma unroll
            for (int j = 0; j < 8; j++) v[j] = (short)f2bf(s[j]);
            *(short8*)(As + (e>>9)*PADW + (e&511)) = v;
            *(short8*)(&g_xb[off]) = v;
        }
    } else {
#pragma unroll
        for (int i = 0; i < 4; i++) {
            const int e = (i*TPB + tid) * 8;
            const int off = base + e;
            float s[8] = {0,0,0,0,0,0,0,0};
            for (int m = 0; m < nk; m++) {
                const short8 fm = *(const short8*)(&g_Fm[m][off]);
#pragma unroll
                for (int j = 0; j < 8; j++)
                    s[j] = fmaf(al[m], bf2f((unsigned short)fm[j]), s[j]);
            }
            short8 v;
#pragma unroll
            for (int j = 0; j < 8; j++) v[j] = (short)f2bf(s[j]);
            *(short8*)(As + (e>>9)*PADW + (e&511)) = v;
            *(short8*)(&g_xb[off]) = v;
        }
    }
    __syncthreads();
    mfma_gemm<0>(g_Wb, lin_b, As, Fs, nullptr);
    __syncthreads();
    float dv[6] = {0,0,0,0,0,0};
    float dself = 0.f;
#pragma unroll
    for (int i = 0; i < 4; i++) {
        const int e = (i*TPB + tid) * 8;
        const int off = base + e, lo = (e>>9)*PADW + (e&511);
        const short8 fv = *(const short8*)(Fs + lo);
        const short8 xv = *(const short8*)(As + lo);
        float gg[8]; short8 gv;
#pragma unroll
        for (int j = 0; j < 8; j++) {
            const float ff = bf2f((unsigned short)fv[j]);
            const float g  = ff - bf2f((unsigned short)xv[j]);
            gg[j] = g; gv[j] = (short)f2bf(g);
            dv[5] = fmaf(ff, ff, dv[5]);
            dself = fmaf(g, g, dself);
        }
        *(short8*)(&g_Fm[idx][off]) = fv;
        *(short8*)(&g_G [idx][off]) = gv;
#pragma unroll
        for (int js = 0; js < MM; js++) {
            if (js != idx && js < nk) {
                const short8 gj = *(const short8*)(&g_G[js][off]);
#pragma unroll
                for (int j = 0; j < 8; j++)
                    dv[js] = fmaf(gg[j], bf2f((unsigned short)gj[j]), dv[js]);
            }
        }
    }
    float vals[6];
#pragma unroll
    for (int j = 0; j < MM; j++) vals[j] = (j == idx) ? (dv[j] + dself) : dv[j];
    vals[5] = dv[5];
    red6(vals, redS, &g_acc[it][b][0]);
}

__global__ void __launch_bounds__(TPB, 4) k_final(const float* __restrict__ bias,
                                                  float* __restrict__ out)
{
    __shared__ __align__(16) unsigned short As[ROWS*PADW];
    const int tid = threadIdx.x;
    const int base = blockIdx.x * (ROWS*FD);
#pragma unroll
    for (int i = 0; i < 4; i++) {
        const int e = (i*TPB + tid) * 8;
        *(short8*)(As + (e>>9)*PADW + (e&511)) = *(const short8*)(&g_xb[base + e]);
    }
    __syncthreads();
    mfma_gemm<1>(g_WbO, bias, As, nullptr, out + base);
}

extern "C" void kernel_launch(void* const* d_in, const int* in_sizes, int n_in,
                              void* d_out, int out_size, void* d_ws, size_t ws_size,
                              hipStream_t stream)
{
    (void)in_sizes; (void)n_in; (void)out_size; (void)d_ws; (void)ws_size;
    const float* x      = (const float*)d_in[0];
    const float* lin_w  = (const float*)d_in[1];
    const float* lin_b  = (const float*)d_in[2];
    const float* weight = (const float*)d_in[3];
    const float* bias   = (const float*)d_in[4];
    float* out = (float*)d_out;

    void* args[] = {(void*)&x, (void*)&lin_w, (void*)&lin_b,
                    (void*)&weight, (void*)&bias, (void*)&out};
    if (hipLaunchCooperativeKernel(reinterpret_cast<const void*>(&k_anderson),
                                   dim3(NBLK), dim3(TPB), args, 0, stream) != hipSuccess) {
        // fallback: proven multi-launch path
        hipLaunchKernelGGL(k_init0, dim3(512),  dim3(256), 0, stream, lin_w, weight);
        hipLaunchKernelGGL(k_init1, dim3(NBLK), dim3(TPB), 0, stream, x, lin_b);
        for (int k = 2; k < MAXIT; k++)
            hipLaunchKernelGGL(k_iter, dim3(NBLK), dim3(TPB), 0, stream, lin_b, k);
        hipLaunchKernelGGL(k_final, dim3(NBLK), dim3(TPB), 0, stream, bias, out);
    }
}

// Round 5
// 793.784 us; speedup vs baseline: 1.6653x; 1.2505x over previous
//
#include <hip/hip_runtime.h>
#include <math.h>

#define FD     512
#define NBATCH 16
#define NROWS  16384
#define ROWS   64              // rows per block
#define NBLK   (NROWS/ROWS)    // 256 blocks = 1 per CU
#define TPB    1024            // 16 waves/block
#define MM     5
#define LAMV   1e-4f
#define MAXIT  50
#define TOLV   0.01f
#define NTOT   8388608
#define PADW   520             // LDS row stride (bf16 elems), 16B aligned

typedef __attribute__((ext_vector_type(8))) short  short8;   // 8 bf16
typedef __attribute__((ext_vector_type(4))) float  float4v;  // MFMA C/D frag

// Persistent device state; fully rewritten (or provably unused) every call.
__device__ unsigned short g_Fm[MM][NTOT];
__device__ unsigned short g_G [MM][NTOT];
__device__ unsigned short g_Wb [FD*FD];        // bf16(lin_w) row-major
__device__ unsigned short g_WbO[FD*FD];        // bf16(weight) row-major
__device__ float g_acc [MAXIT-2][NBATCH][8];   // per-iter Gram-row dots [0..4], ||f||^2 [5]
__device__ float g_acc0[NBATCH][8];            // init dots d00,d01,d11
__device__ float g_alpha[8];                   // alphas of last LIVE iteration
__device__ int   g_lastk;                      // k of last live iteration (>=2)

static __device__ __forceinline__ unsigned short f2bf(float f) {
    unsigned u = __float_as_uint(f);
    u += 0x7fff + ((u >> 16) & 1);             // RNE
    return (unsigned short)(u >> 16);
}
static __device__ __forceinline__ float bf2f(unsigned short s) {
    return __uint_as_float(((unsigned)s) << 16);
}

// 64x512 tile GEMM: D = A(64x512 bf16, LDS) @ W^T + bias.
// 16 waves; wave owns 32 output cols (2 ct) x all 64 rows (4 r16).
// A[m=lane&15][k=quad*8+j], B[k=quad*8+j][n=lane&15], C/D col=lane&15,
// row=quad*4+reg (verified m89/m91 layouts).
// MODE 0: bf16 -> FsOut (LDS). MODE 1: fp32 -> gout (global tile base).
template<int MODE>
static __device__ __forceinline__ void mfma_gemm(const unsigned short* __restrict__ Wb,
                                                 const float* __restrict__ bvec,
                                                 const unsigned short* AsIn,
                                                 unsigned short* FsOut,
                                                 float* __restrict__ gout)
{
    const int lane = threadIdx.x & 63;
    const int wv   = threadIdx.x >> 6;     // 0..15
    const int lm   = lane & 15;
    const int quad = lane >> 4;
    float4v acc[4][2];
#pragma unroll
    for (int ct = 0; ct < 2; ct++) {
        const float b = bvec[wv*32 + ct*16 + lm];
#pragma unroll
        for (int r16 = 0; r16 < 4; r16++) {
            acc[r16][ct][0]=b; acc[r16][ct][1]=b; acc[r16][ct][2]=b; acc[r16][ct][3]=b;
        }
    }
#pragma unroll
    for (int q = 0; q < 4; q++) {
#pragma unroll
        for (int kb = 0; kb < 4; kb++) {
            const int ko = q*128 + kb*32 + quad*8;
            short8 bf[2];
#pragma unroll
            for (int ct = 0; ct < 2; ct++)
                bf[ct] = *(const short8*)(Wb + (wv*32 + ct*16 + lm)*FD + ko);
            short8 af[4];
#pragma unroll
            for (int r16 = 0; r16 < 4; r16++)
                af[r16] = *(const short8*)(AsIn + (r16*16 + lm)*PADW + ko);
#pragma unroll
            for (int r16 = 0; r16 < 4; r16++) {
                acc[r16][0] = __builtin_amdgcn_mfma_f32_16x16x32_bf16(af[r16], bf[0], acc[r16][0], 0,0,0);
                acc[r16][1] = __builtin_amdgcn_mfma_f32_16x16x32_bf16(af[r16], bf[1], acc[r16][1], 0,0,0);
            }
        }
    }
#pragma unroll
    for (int ct = 0; ct < 2; ct++) {
        const int c = wv*32 + ct*16 + lm;
#pragma unroll
        for (int r16 = 0; r16 < 4; r16++)
#pragma unroll
            for (int r = 0; r < 4; r++) {
                const int row = r16*16 + quad*4 + r;
                if (MODE == 0) FsOut[row*PADW + c] = f2bf(acc[r16][ct][r]);
                else           gout[row*FD + c]    = acc[r16][ct][r];
            }
    }
}

static __device__ __forceinline__ void red6(const float vals[6], float (*redS)[8], float* accrow)
{
    const int lane = threadIdx.x & 63, wv = threadIdx.x >> 6;   // wv 0..15
#pragma unroll
    for (int j = 0; j < 6; j++) {
        float v = vals[j];
#pragma unroll
        for (int o = 32; o; o >>= 1) v += __shfl_down(v, o);
        if (lane == 0) redS[wv][j] = v;
    }
    __syncthreads();
    if (threadIdx.x < 6) {
        float s = 0.f;
#pragma unroll
        for (int w = 0; w < 16; w++) s += redS[w][threadIdx.x];
        atomicAdd(accrow + threadIdx.x, s);   // device-scope
    }
}

// ---------------- init0: weight bf16 conversion + zero accumulators ----------
__global__ void __launch_bounds__(256) k_init0(const float* __restrict__ lin_w,
                                               const float* __restrict__ weight)
{
    const int i0 = blockIdx.x*256 + threadIdx.x, stride = gridDim.x*256;
    for (int i = i0; i < FD*FD; i += stride) {
        g_Wb [i] = f2bf(lin_w[i]);
        g_WbO[i] = f2bf(weight[i]);
    }
    float* a = &g_acc[0][0][0];
    for (int i = i0; i < (MAXIT-2)*NBATCH*8; i += stride) a[i] = 0.f;
    float* a0 = &g_acc0[0][0];
    for (int i = i0; i < NBATCH*8; i += stride) a0[i] = 0.f;
}

// ---------------- init1: F0=f(x~0), F1=f(F~0), G0, G1, init Gram dots --------
__global__ void __launch_bounds__(TPB, 4) k_init1(const float* __restrict__ x,
                                                  const float* __restrict__ lin_b)
{
    __shared__ __align__(16) unsigned short As[ROWS*PADW];
    __shared__ __align__(16) unsigned short Fs[ROWS*PADW];
    __shared__ float redS[16][8];
    const int tid = threadIdx.x;
    const int t = blockIdx.x, b = t >> 4;
    const int base = t * (ROWS*FD);

#pragma unroll
    for (int i = 0; i < 4; i++) {               // bf16(x0 tile) -> As
        const int e = (i*TPB + tid) * 8;
        const float4 a0 = *(const float4*)(x + base + e);
        const float4 a1 = *(const float4*)(x + base + e + 4);
        short8 v;
        v[0]=f2bf(a0.x); v[1]=f2bf(a0.y); v[2]=f2bf(a0.z); v[3]=f2bf(a0.w);
        v[4]=f2bf(a1.x); v[5]=f2bf(a1.y); v[6]=f2bf(a1.z); v[7]=f2bf(a1.w);
        *(short8*)(As + (e>>9)*PADW + (e&511)) = v;
    }
    __syncthreads();
    mfma_gemm<0>(g_Wb, lin_b, As, Fs, nullptr);   // Fs = bf16(f(x~0))
    __syncthreads();
    float d00 = 0.f;
#pragma unroll
    for (int i = 0; i < 4; i++) {
        const int e = (i*TPB + tid) * 8;
        const int off = base + e, lo = (e>>9)*PADW + (e&511);
        const short8 fv = *(const short8*)(Fs + lo);
        const short8 xv = *(const short8*)(As + lo);
        short8 gv;
#pragma unroll
        for (int j = 0; j < 8; j++) {
            const float g = bf2f((unsigned short)fv[j]) - bf2f((unsigned short)xv[j]);
            gv[j] = (short)f2bf(g);
            d00 = fmaf(g, g, d00);
        }
        *(short8*)(&g_Fm[0][off]) = fv;
        *(short8*)(&g_G [0][off]) = gv;
    }
    __syncthreads();
    mfma_gemm<0>(g_Wb, lin_b, Fs, As, nullptr);   // As = bf16(f(F~0))
    __syncthreads();
    float d01 = 0.f, d11 = 0.f;
#pragma unroll
    for (int i = 0; i < 4; i++) {
        const int e = (i*TPB + tid) * 8;
        const int off = base + e, lo = (e>>9)*PADW + (e&511);
        const short8 f1 = *(const short8*)(As + lo);
        const short8 f0 = *(const short8*)(Fs + lo);
        const short8 g0 = *(const short8*)(&g_G[0][off]);
        short8 gv;
#pragma unroll
        for (int j = 0; j < 8; j++) {
            const float g = bf2f((unsigned short)f1[j]) - bf2f((unsigned short)f0[j]);
            gv[j] = (short)f2bf(g);
            d11 = fmaf(g, g, d11);
            d01 = fmaf(bf2f((unsigned short)g0[j]), g, d01);
        }
        *(short8*)(&g_Fm[1][off]) = f1;
        *(short8*)(&g_G [1][off]) = gv;
    }
    const float vals[6] = {d00, d01, d11, 0.f, 0.f, 0.f};
    red6(vals, redS, &g_acc0[b][0]);
}

// ---------------- one Anderson iteration (k = 2..49) -------------------------
__global__ void __launch_bounds__(TPB, 4) k_iter(const float* __restrict__ lin_b, int k)
{
    __shared__ __align__(16) unsigned short As[ROWS*PADW];
    __shared__ __align__(16) unsigned short Fs[ROWS*PADW];
    __shared__ float gramS[MM][MM];
    __shared__ float alphaS[MM];
    __shared__ float Hs[48];
    __shared__ float redS[16][8];
    __shared__ float gAs[MM][MM];   // Gram window cache (wave-1 parallel load)
    __shared__ float ga0S[3];       // d00,d01,d11
    __shared__ float sres;

    const int tid = threadIdx.x;
    const int t = blockIdx.x, b = t >> 4;
    const int base = t * (ROWS*FD);
    const int it = k - 2, idx = k % MM, nk = (k < MM) ? k : MM;
    const int j0 = (k - 5 > 2) ? (k - 5) : 2;

    // Early prefetch of pass-1 Fm reads, chunks 0-1 (own tile, written by a
    // PREVIOUS launch -> visible; valid to issue regardless of the stop check,
    // hides the residual/solve serial section under memory latency).
    short8 pf0[MM], pf1[MM];
#pragma unroll
    for (int m = 0; m < MM; m++) if (m < nk) {
        pf0[m] = *(const short8*)(&g_Fm[m][base + (0*TPB + tid)*8]);
        pf1[m] = *(const short8*)(&g_Fm[m][base + (1*TPB + tid)*8]);
    }

    // wave 0: residual of iteration k-1 (skipped iterations leave zeros)
    if (k > 2 && (tid >> 6) == 0) {
        float v = 0.f;
        if (tid < 32) {
            const int bb = tid & 15;
            const int jj = (tid < 16) ? ((k-1) % MM) : 5;
            v = g_acc[it-1][bb][jj];
        }
        v += __shfl_xor(v, 1); v += __shfl_xor(v, 2);
        v += __shfl_xor(v, 4); v += __shfl_xor(v, 8);
        const float num = __shfl(v, 0), den = __shfl(v, 16);
        if (tid == 0) sres = sqrtf(num) / (1e-5f + sqrtf(den));
    }
    // wave 1: Gram window + init dots -> LDS (kills ~25 serialized lane-0 loads)
    if ((tid >> 6) == 1) {
        const int l = tid & 63;
        if (l < 25) {
            const int jj = j0 + l/5;
            if (jj < k) gAs[l/5][l%5] = g_acc[jj-2][b][l%5];
        } else if (l < 28) {
            ga0S[l-25] = g_acc0[b][l-25];
        }
    }
    __syncthreads();
    if (k > 2 && sres < TOLV) return;            // uniform across grid

    // --- Gram replay (chronological, last <=5 iterations) + bordered 6x6 solve
    if (tid == 0) {
#pragma unroll
        for (int i = 0; i < MM; i++)
#pragma unroll
            for (int j = 0; j < MM; j++) gramS[i][j] = 0.f;
        gramS[0][0] = ga0S[0];
        gramS[0][1] = gramS[1][0] = ga0S[1];
        gramS[1][1] = ga0S[2];
        for (int j = j0; j < k; j++) {
            const int ij = j % MM, nkj = (j < MM) ? j : MM;
            for (int c = 0; c < MM; c++)
                if (c < nkj || c == ij) {
                    const float vv = gAs[j - j0][c];
                    gramS[ij][c] = vv; gramS[c][ij] = vv;
                }
        }
        float* H = Hs;                            // 6x7 augmented
        for (int i = 0; i < 42; i++) H[i] = 0.f;
        for (int j = 0; j < nk; j++) { H[1+j] = 1.f; H[(1+j)*7] = 1.f; }
#pragma unroll
        for (int i = 0; i < MM; i++) H[(1+i)*7 + (1+i)] = LAMV;
        for (int i = 0; i < nk; i++)
            for (int j = 0; j < nk; j++)
                H[(1+i)*7 + (1+j)] = gramS[i][j] + (i == j ? LAMV : 0.f);
        H[6] = 1.f;                               // rhs = e0
        for (int col = 0; col < 6; col++) {
            int p = col; float mx = fabsf(H[col*7+col]);
            for (int r2 = col+1; r2 < 6; r2++) {
                const float vv = fabsf(H[r2*7+col]);
                if (vv > mx) { mx = vv; p = r2; }
            }
            if (p != col)
                for (int j = col; j < 7; j++) { const float tt = H[col*7+j]; H[col*7+j] = H[p*7+j]; H[p*7+j] = tt; }
            const float piv = H[col*7+col];
            for (int r2 = col+1; r2 < 6; r2++) {
                const float fct = H[r2*7+col] / piv;
                for (int j = col+1; j < 7; j++) H[r2*7+j] -= fct * H[col*7+j];
            }
        }
        for (int r2 = 5; r2 >= 0; r2--) {
            float s = H[r2*7+6];
            for (int j = r2+1; j < 6; j++) s -= H[r2*7+j] * H[j*7+6];
            H[r2*7+6] = s / H[r2*7+r2];
        }
#pragma unroll
        for (int m = 0; m < MM; m++) alphaS[m] = H[(1+m)*7+6];
        if (t == 0) {                             // publish for k_final
#pragma unroll
            for (int m = 0; m < MM; m++) g_alpha[m] = H[(1+m)*7+6];
            g_lastk = k;
        }
    }
    __syncthreads();

    float al[MM];
#pragma unroll
    for (int m = 0; m < MM; m++) al[m] = alphaS[m];

    // --- pass 1: x~ = bf16(sum_m alpha_m Fm[m]) -> As (no g_xb stream)
#pragma unroll
    for (int i = 0; i < 4; i++) {
        const int e = (i*TPB + tid) * 8;
        const int off = base + e;
        float s[8] = {0,0,0,0,0,0,0,0};
#pragma unroll
        for (int m = 0; m < MM; m++) if (m < nk) {
            short8 fm;
            if (i == 0)      fm = pf0[m];
            else if (i == 1) fm = pf1[m];
            else             fm = *(const short8*)(&g_Fm[m][off]);
#pragma unroll
            for (int j = 0; j < 8; j++)
                s[j] = fmaf(al[m], bf2f((unsigned short)fm[j]), s[j]);
        }
        short8 v;
#pragma unroll
        for (int j = 0; j < 8; j++) v[j] = (short)f2bf(s[j]);
        *(short8*)(As + (e>>9)*PADW + (e&511)) = v;
    }
    __syncthreads();
    // --- pass 2: Fs = bf16(x~ @ lin_w^T + lin_b)
    mfma_gemm<0>(g_Wb, lin_b, As, Fs, nullptr);
    __syncthreads();
    // --- pass 3: state writes + Gram-row dots + residual partials
    float dv[6] = {0,0,0,0,0,0};
    float dself = 0.f;
#pragma unroll
    for (int i = 0; i < 4; i++) {
        const int e = (i*TPB + tid) * 8;
        const int off = base + e, lo = (e>>9)*PADW + (e&511);
        const short8 fv = *(const short8*)(Fs + lo);
        const short8 xv = *(const short8*)(As + lo);
        float gg[8]; short8 gv;
#pragma unroll
        for (int j = 0; j < 8; j++) {
            const float ff = bf2f((unsigned short)fv[j]);
            const float g  = ff - bf2f((unsigned short)xv[j]);
            gg[j] = g; gv[j] = (short)f2bf(g);
            dv[5] = fmaf(ff, ff, dv[5]);
            dself = fmaf(g, g, dself);
        }
        *(short8*)(&g_Fm[idx][off]) = fv;
        *(short8*)(&g_G [idx][off]) = gv;
#pragma unroll
        for (int js = 0; js < MM; js++) {
            if (js != idx && js < nk) {
                const short8 gj = *(const short8*)(&g_G[js][off]);
#pragma unroll
                for (int j = 0; j < 8; j++)
                    dv[js] = fmaf(gg[j], bf2f((unsigned short)gj[j]), dv[js]);
            }
        }
    }
    float vals[6];
#pragma unroll
    for (int j = 0; j < MM; j++) vals[j] = (j == idx) ? (dv[j] + dself) : dv[j];
    vals[5] = dv[5];
    red6(vals, redS, &g_acc[it][b][0]);
}

// ---------------- final: recompute x~last, out = x~ @ weight^T + bias --------
// Bit-identical to k_iter's pass 1 (same fmaf order, same alphas via g_alpha),
// then the MODE-1 GEMM. Replaces the per-iteration g_xb stream.
__global__ void __launch_bounds__(TPB, 4) k_final(const float* __restrict__ bias,
                                                  float* __restrict__ out)
{
    __shared__ __align__(16) unsigned short As[ROWS*PADW];
    __shared__ float alphaS[MM];
    __shared__ int   nkS;
    const int tid = threadIdx.x;
    const int base = blockIdx.x * (ROWS*FD);

    if (tid == 0) {
        const int lk = g_lastk;
        nkS = (lk < MM) ? lk : MM;
#pragma unroll
        for (int m = 0; m < MM; m++) alphaS[m] = g_alpha[m];
    }
    __syncthreads();
    const int nk = nkS;
    float al[MM];
#pragma unroll
    for (int m = 0; m < MM; m++) al[m] = alphaS[m];

#pragma unroll
    for (int i = 0; i < 4; i++) {
        const int e = (i*TPB + tid) * 8;
        const int off = base + e;
        float s[8] = {0,0,0,0,0,0,0,0};
#pragma unroll
        for (int m = 0; m < MM; m++) if (m < nk) {
            const short8 fm = *(const short8*)(&g_Fm[m][off]);
#pragma unroll
            for (int j = 0; j < 8; j++)
                s[j] = fmaf(al[m], bf2f((unsigned short)fm[j]), s[j]);
        }
        short8 v;
#pragma unroll
        for (int j = 0; j < 8; j++) v[j] = (short)f2bf(s[j]);
        *(short8*)(As + (e>>9)*PADW + (e&511)) = v;
    }
    __syncthreads();
    mfma_gemm<1>(g_WbO, bias, As, nullptr, out + base);
}

extern "C" void kernel_launch(void* const* d_in, const int* in_sizes, int n_in,
                              void* d_out, int out_size, void* d_ws, size_t ws_size,
                              hipStream_t stream)
{
    (void)in_sizes; (void)n_in; (void)out_size; (void)d_ws; (void)ws_size;
    const float* x      = (const float*)d_in[0];
    const float* lin_w  = (const float*)d_in[1];
    const float* lin_b  = (const float*)d_in[2];
    const float* weight = (const float*)d_in[3];
    const float* bias   = (const float*)d_in[4];
    float* out = (float*)d_out;

    hipLaunchKernelGGL(k_init0, dim3(512),  dim3(256), 0, stream, lin_w, weight);
    hipLaunchKernelGGL(k_init1, dim3(NBLK), dim3(TPB), 0, stream, x, lin_b);
    for (int k = 2; k < MAXIT; k++)
        hipLaunchKernelGGL(k_iter, dim3(NBLK), dim3(TPB), 0, stream, lin_b, k);
    hipLaunchKernelGGL(k_final, dim3(NBLK), dim3(TPB), 0, stream, bias, out);
}

// Round 6
// 627.426 us; speedup vs baseline: 2.1069x; 1.2651x over previous
//
#include <hip/hip_runtime.h>
#include <math.h>

#define FD     512
#define NBATCH 16
#define NROWS  16384
#define ROWS   64              // rows per block
#define NBLK   (NROWS/ROWS)    // 256 blocks = 1 per CU
#define TPB    1024            // 16 waves/block
#define MM     5
#define LAMV   1e-4f
#define MAXIT  50
#define TOLV   0.01f
#define NTOT   8388608
#define PADW   520             // LDS row stride (bf16 elems), 16B aligned

typedef __attribute__((ext_vector_type(8))) short  short8;   // 8 bf16
typedef __attribute__((ext_vector_type(4))) float  float4v;  // MFMA C/D frag

// Persistent device state; fully rewritten (or provably unused) every call.
__device__ unsigned short g_Fm[MM][NTOT];
__device__ unsigned short g_G [MM][NTOT];
__device__ unsigned short g_Wb [FD*FD];        // bf16(lin_w) row-major
__device__ unsigned short g_WbO[FD*FD];        // bf16(weight) row-major
__device__ float g_acc [MAXIT-2][NBATCH][8];   // per-iter Gram-row dots [0..4], ||f||^2 [5]
__device__ float g_acc0[NBATCH][8];            // init dots d00,d01,d11
__device__ float g_alpha[8];                   // alphas of last LIVE iteration
__device__ int   g_lastk;                      // k of last live iteration (>=2)

static __device__ __forceinline__ unsigned short f2bf(float f) {
    unsigned u = __float_as_uint(f);
    u += 0x7fff + ((u >> 16) & 1);             // RNE
    return (unsigned short)(u >> 16);
}
static __device__ __forceinline__ float bf2f(unsigned short s) {
    return __uint_as_float(((unsigned)s) << 16);
}

// 64x512 tile GEMM: D = A(64x512 bf16, LDS) @ W^T + bias.
// 16 waves; wave owns 32 output cols (2 ct) x all 64 rows (4 r16).
// A[m=lane&15][k=quad*8+j], B[k=quad*8+j][n=lane&15], C/D col=lane&15,
// row=quad*4+reg (verified m89/m91 layouts).
// MODE 0: bf16 -> FsOut (LDS). MODE 1: fp32 -> gout (global tile base).
template<int MODE>
static __device__ __forceinline__ void mfma_gemm(const unsigned short* __restrict__ Wb,
                                                 const float* __restrict__ bvec,
                                                 const unsigned short* AsIn,
                                                 unsigned short* FsOut,
                                                 float* __restrict__ gout)
{
    const int lane = threadIdx.x & 63;
    const int wv   = threadIdx.x >> 6;     // 0..15
    const int lm   = lane & 15;
    const int quad = lane >> 4;
    float4v acc[4][2];
#pragma unroll
    for (int ct = 0; ct < 2; ct++) {
        const float b = bvec[wv*32 + ct*16 + lm];
#pragma unroll
        for (int r16 = 0; r16 < 4; r16++) {
            acc[r16][ct][0]=b; acc[r16][ct][1]=b; acc[r16][ct][2]=b; acc[r16][ct][3]=b;
        }
    }
#pragma unroll
    for (int q = 0; q < 4; q++) {
#pragma unroll
        for (int kb = 0; kb < 4; kb++) {
            const int ko = q*128 + kb*32 + quad*8;
            short8 bf[2];
#pragma unroll
            for (int ct = 0; ct < 2; ct++)
                bf[ct] = *(const short8*)(Wb + (wv*32 + ct*16 + lm)*FD + ko);
            short8 af[4];
#pragma unroll
            for (int r16 = 0; r16 < 4; r16++)
                af[r16] = *(const short8*)(AsIn + (r16*16 + lm)*PADW + ko);
#pragma unroll
            for (int r16 = 0; r16 < 4; r16++) {
                acc[r16][0] = __builtin_amdgcn_mfma_f32_16x16x32_bf16(af[r16], bf[0], acc[r16][0], 0,0,0);
                acc[r16][1] = __builtin_amdgcn_mfma_f32_16x16x32_bf16(af[r16], bf[1], acc[r16][1], 0,0,0);
            }
        }
    }
#pragma unroll
    for (int ct = 0; ct < 2; ct++) {
        const int c = wv*32 + ct*16 + lm;
#pragma unroll
        for (int r16 = 0; r16 < 4; r16++)
#pragma unroll
            for (int r = 0; r < 4; r++) {
                const int row = r16*16 + quad*4 + r;
                if (MODE == 0) FsOut[row*PADW + c] = f2bf(acc[r16][ct][r]);
                else           gout[row*FD + c]    = acc[r16][ct][r];
            }
    }
}

static __device__ __forceinline__ void red6(const float vals[6], float (*redS)[8], float* accrow)
{
    const int lane = threadIdx.x & 63, wv = threadIdx.x >> 6;   // wv 0..15
#pragma unroll
    for (int j = 0; j < 6; j++) {
        float v = vals[j];
#pragma unroll
        for (int o = 32; o; o >>= 1) v += __shfl_down(v, o);
        if (lane == 0) redS[wv][j] = v;
    }
    __syncthreads();
    if (threadIdx.x < 6) {
        float s = 0.f;
#pragma unroll
        for (int w = 0; w < 16; w++) s += redS[w][threadIdx.x];
        atomicAdd(accrow + threadIdx.x, s);   // device-scope
    }
}

// ---------------- init0: weight bf16 conversion + zero accumulators ----------
__global__ void __launch_bounds__(256) k_init0(const float* __restrict__ lin_w,
                                               const float* __restrict__ weight)
{
    const int i0 = blockIdx.x*256 + threadIdx.x, stride = gridDim.x*256;
    for (int i = i0; i < FD*FD; i += stride) {
        g_Wb [i] = f2bf(lin_w[i]);
        g_WbO[i] = f2bf(weight[i]);
    }
    float* a = &g_acc[0][0][0];
    for (int i = i0; i < (MAXIT-2)*NBATCH*8; i += stride) a[i] = 0.f;
    float* a0 = &g_acc0[0][0];
    for (int i = i0; i < NBATCH*8; i += stride) a0[i] = 0.f;
}

// ---------------- init1: F0=f(x~0), F1=f(F~0), G0, G1, init Gram dots --------
__global__ void __launch_bounds__(TPB, 4) k_init1(const float* __restrict__ x,
                                                  const float* __restrict__ lin_b)
{
    __shared__ __align__(16) unsigned short As[ROWS*PADW];
    __shared__ __align__(16) unsigned short Fs[ROWS*PADW];
    __shared__ float redS[16][8];
    const int tid = threadIdx.x;
    const int t = blockIdx.x, b = t >> 4;
    const int base = t * (ROWS*FD);

#pragma unroll
    for (int i = 0; i < 4; i++) {               // bf16(x0 tile) -> As
        const int e = (i*TPB + tid) * 8;
        const float4 a0 = *(const float4*)(x + base + e);
        const float4 a1 = *(const float4*)(x + base + e + 4);
        short8 v;
        v[0]=f2bf(a0.x); v[1]=f2bf(a0.y); v[2]=f2bf(a0.z); v[3]=f2bf(a0.w);
        v[4]=f2bf(a1.x); v[5]=f2bf(a1.y); v[6]=f2bf(a1.z); v[7]=f2bf(a1.w);
        *(short8*)(As + (e>>9)*PADW + (e&511)) = v;
    }
    __syncthreads();
    mfma_gemm<0>(g_Wb, lin_b, As, Fs, nullptr);   // Fs = bf16(f(x~0))
    __syncthreads();
    float d00 = 0.f;
#pragma unroll
    for (int i = 0; i < 4; i++) {
        const int e = (i*TPB + tid) * 8;
        const int off = base + e, lo = (e>>9)*PADW + (e&511);
        const short8 fv = *(const short8*)(Fs + lo);
        const short8 xv = *(const short8*)(As + lo);
        short8 gv;
#pragma unroll
        for (int j = 0; j < 8; j++) {
            const float g = bf2f((unsigned short)fv[j]) - bf2f((unsigned short)xv[j]);
            gv[j] = (short)f2bf(g);
            d00 = fmaf(g, g, d00);
        }
        *(short8*)(&g_Fm[0][off]) = fv;
        *(short8*)(&g_G [0][off]) = gv;
    }
    __syncthreads();
    mfma_gemm<0>(g_Wb, lin_b, Fs, As, nullptr);   // As = bf16(f(F~0))
    __syncthreads();
    float d01 = 0.f, d11 = 0.f;
#pragma unroll
    for (int i = 0; i < 4; i++) {
        const int e = (i*TPB + tid) * 8;
        const int off = base + e, lo = (e>>9)*PADW + (e&511);
        const short8 f1 = *(const short8*)(As + lo);
        const short8 f0 = *(const short8*)(Fs + lo);
        const short8 g0 = *(const short8*)(&g_G[0][off]);
        short8 gv;
#pragma unroll
        for (int j = 0; j < 8; j++) {
            const float g = bf2f((unsigned short)f1[j]) - bf2f((unsigned short)f0[j]);
            gv[j] = (short)f2bf(g);
            d11 = fmaf(g, g, d11);
            d01 = fmaf(bf2f((unsigned short)g0[j]), g, d01);
        }
        *(short8*)(&g_Fm[1][off]) = f1;
        *(short8*)(&g_G [1][off]) = gv;
    }
    const float vals[6] = {d00, d01, d11, 0.f, 0.f, 0.f};
    red6(vals, redS, &g_acc0[b][0]);
}

// ---------------- one Anderson iteration (k = 2..49) -------------------------
__global__ void __launch_bounds__(TPB, 4) k_iter(const float* __restrict__ lin_b, int k)
{
    __shared__ __align__(16) unsigned short As[ROWS*PADW];
    __shared__ __align__(16) unsigned short Fs[ROWS*PADW];
    __shared__ float gramS[MM][MM];
    __shared__ float alphaS[MM];
    __shared__ float Hs[48];
    __shared__ float redS[16][8];
    __shared__ float gAs[MM][MM];   // Gram window cache (wave-1 parallel load)
    __shared__ float ga0S[3];       // d00,d01,d11
    __shared__ float sres;

    const int tid = threadIdx.x;
    const int t = blockIdx.x, b = t >> 4;
    const int base = t * (ROWS*FD);
    const int it = k - 2, idx = k % MM, nk = (k < MM) ? k : MM;
    const int j0 = (k - 5 > 2) ? (k - 5) : 2;

    // wave 0: residual of iteration k-1 (skipped iterations leave zeros)
    if (k > 2 && (tid >> 6) == 0) {
        float v = 0.f;
        if (tid < 32) {
            const int bb = tid & 15;
            const int jj = (tid < 16) ? ((k-1) % MM) : 5;
            v = g_acc[it-1][bb][jj];
        }
        v += __shfl_xor(v, 1); v += __shfl_xor(v, 2);
        v += __shfl_xor(v, 4); v += __shfl_xor(v, 8);
        const float num = __shfl(v, 0), den = __shfl(v, 16);
        if (tid == 0) sres = sqrtf(num) / (1e-5f + sqrtf(den));
    }
    // wave 1: Gram window + init dots -> LDS (kills ~25 serialized lane-0 loads)
    if ((tid >> 6) == 1) {
        const int l = tid & 63;
        if (l < 25) {
            const int jj = j0 + l/5;
            if (jj < k) gAs[l/5][l%5] = g_acc[jj-2][b][l%5];
        } else if (l < 28) {
            ga0S[l-25] = g_acc0[b][l-25];
        }
    }
    __syncthreads();
    if (k > 2 && sres < TOLV) return;            // uniform across grid
    // NOTE: dead launches (post-convergence) return HERE with only the tiny
    // residual/Gram loads in flight (~2.5 us). The Fm prefetch below must stay
    // AFTER this gate: issuing it pre-gate cost ~40 MB x ~35 dead launches
    // (round-5 regression, 794 us vs 630).

    // Prefetch pass-1 Fm reads, chunks 0-1 (own tile). Issued by all waves
    // before lane 0's serial solve, so the ~2-4 us solve hides the latency.
    short8 pf0[MM], pf1[MM];
#pragma unroll
    for (int m = 0; m < MM; m++) if (m < nk) {
        pf0[m] = *(const short8*)(&g_Fm[m][base + (0*TPB + tid)*8]);
        pf1[m] = *(const short8*)(&g_Fm[m][base + (1*TPB + tid)*8]);
    }
    __builtin_amdgcn_sched_barrier(0);           // keep loads above the solve

    // --- Gram replay (chronological, last <=5 iterations) + bordered 6x6 solve
    if (tid == 0) {
#pragma unroll
        for (int i = 0; i < MM; i++)
#pragma unroll
            for (int j = 0; j < MM; j++) gramS[i][j] = 0.f;
        gramS[0][0] = ga0S[0];
        gramS[0][1] = gramS[1][0] = ga0S[1];
        gramS[1][1] = ga0S[2];
        for (int j = j0; j < k; j++) {
            const int ij = j % MM, nkj = (j < MM) ? j : MM;
            for (int c = 0; c < MM; c++)
                if (c < nkj || c == ij) {
                    const float vv = gAs[j - j0][c];
                    gramS[ij][c] = vv; gramS[c][ij] = vv;
                }
        }
        float* H = Hs;                            // 6x7 augmented
        for (int i = 0; i < 42; i++) H[i] = 0.f;
        for (int j = 0; j < nk; j++) { H[1+j] = 1.f; H[(1+j)*7] = 1.f; }
#pragma unroll
        for (int i = 0; i < MM; i++) H[(1+i)*7 + (1+i)] = LAMV;
        for (int i = 0; i < nk; i++)
            for (int j = 0; j < nk; j++)
                H[(1+i)*7 + (1+j)] = gramS[i][j] + (i == j ? LAMV : 0.f);
        H[6] = 1.f;                               // rhs = e0
        for (int col = 0; col < 6; col++) {
            int p = col; float mx = fabsf(H[col*7+col]);
            for (int r2 = col+1; r2 < 6; r2++) {
                const float vv = fabsf(H[r2*7+col]);
                if (vv > mx) { mx = vv; p = r2; }
            }
            if (p != col)
                for (int j = col; j < 7; j++) { const float tt = H[col*7+j]; H[col*7+j] = H[p*7+j]; H[p*7+j] = tt; }
            const float piv = H[col*7+col];
            for (int r2 = col+1; r2 < 6; r2++) {
                const float fct = H[r2*7+col] / piv;
                for (int j = col+1; j < 7; j++) H[r2*7+j] -= fct * H[col*7+j];
            }
        }
        for (int r2 = 5; r2 >= 0; r2--) {
            float s = H[r2*7+6];
            for (int j = r2+1; j < 6; j++) s -= H[r2*7+j] * H[j*7+6];
            H[r2*7+6] = s / H[r2*7+r2];
        }
#pragma unroll
        for (int m = 0; m < MM; m++) alphaS[m] = H[(1+m)*7+6];
        if (t == 0) {                             // publish for k_final
#pragma unroll
            for (int m = 0; m < MM; m++) g_alpha[m] = H[(1+m)*7+6];
            g_lastk = k;
        }
    }
    __syncthreads();

    float al[MM];
#pragma unroll
    for (int m = 0; m < MM; m++) al[m] = alphaS[m];

    // --- pass 1: x~ = bf16(sum_m alpha_m Fm[m]) -> As (no g_xb stream)
#pragma unroll
    for (int i = 0; i < 4; i++) {
        const int e = (i*TPB + tid) * 8;
        const int off = base + e;
        float s[8] = {0,0,0,0,0,0,0,0};
#pragma unroll
        for (int m = 0; m < MM; m++) if (m < nk) {
            short8 fm;
            if (i == 0)      fm = pf0[m];
            else if (i == 1) fm = pf1[m];
            else             fm = *(const short8*)(&g_Fm[m][off]);
#pragma unroll
            for (int j = 0; j < 8; j++)
                s[j] = fmaf(al[m], bf2f((unsigned short)fm[j]), s[j]);
        }
        short8 v;
#pragma unroll
        for (int j = 0; j < 8; j++) v[j] = (short)f2bf(s[j]);
        *(short8*)(As + (e>>9)*PADW + (e&511)) = v;
    }
    __syncthreads();
    // --- pass 2: Fs = bf16(x~ @ lin_w^T + lin_b)
    mfma_gemm<0>(g_Wb, lin_b, As, Fs, nullptr);
    __syncthreads();
    // --- pass 3: state writes + Gram-row dots + residual partials
    float dv[6] = {0,0,0,0,0,0};
    float dself = 0.f;
#pragma unroll
    for (int i = 0; i < 4; i++) {
        const int e = (i*TPB + tid) * 8;
        const int off = base + e, lo = (e>>9)*PADW + (e&511);
        const short8 fv = *(const short8*)(Fs + lo);
        const short8 xv = *(const short8*)(As + lo);
        float gg[8]; short8 gv;
#pragma unroll
        for (int j = 0; j < 8; j++) {
            const float ff = bf2f((unsigned short)fv[j]);
            const float g  = ff - bf2f((unsigned short)xv[j]);
            gg[j] = g; gv[j] = (short)f2bf(g);
            dv[5] = fmaf(ff, ff, dv[5]);
            dself = fmaf(g, g, dself);
        }
        *(short8*)(&g_Fm[idx][off]) = fv;
        *(short8*)(&g_G [idx][off]) = gv;
#pragma unroll
        for (int js = 0; js < MM; js++) {
            if (js != idx && js < nk) {
                const short8 gj = *(const short8*)(&g_G[js][off]);
#pragma unroll
                for (int j = 0; j < 8; j++)
                    dv[js] = fmaf(gg[j], bf2f((unsigned short)gj[j]), dv[js]);
            }
        }
    }
    float vals[6];
#pragma unroll
    for (int j = 0; j < MM; j++) vals[j] = (j == idx) ? (dv[j] + dself) : dv[j];
    vals[5] = dv[5];
    red6(vals, redS, &g_acc[it][b][0]);
}

// ---------------- final: recompute x~last, out = x~ @ weight^T + bias --------
// Bit-identical to k_iter's pass 1 (same fmaf order, same alphas via g_alpha),
// then the MODE-1 GEMM. Replaces the per-iteration g_xb stream.
__global__ void __launch_bounds__(TPB, 4) k_final(const float* __restrict__ bias,
                                                  float* __restrict__ out)
{
    __shared__ __align__(16) unsigned short As[ROWS*PADW];
    __shared__ float alphaS[MM];
    __shared__ int   nkS;
    const int tid = threadIdx.x;
    const int base = blockIdx.x * (ROWS*FD);

    if (tid == 0) {
        const int lk = g_lastk;
        nkS = (lk < MM) ? lk : MM;
#pragma unroll
        for (int m = 0; m < MM; m++) alphaS[m] = g_alpha[m];
    }
    __syncthreads();
    const int nk = nkS;
    float al[MM];
#pragma unroll
    for (int m = 0; m < MM; m++) al[m] = alphaS[m];

#pragma unroll
    for (int i = 0; i < 4; i++) {
        const int e = (i*TPB + tid) * 8;
        const int off = base + e;
        float s[8] = {0,0,0,0,0,0,0,0};
#pragma unroll
        for (int m = 0; m < MM; m++) if (m < nk) {
            const short8 fm = *(const short8*)(&g_Fm[m][off]);
#pragma unroll
            for (int j = 0; j < 8; j++)
                s[j] = fmaf(al[m], bf2f((unsigned short)fm[j]), s[j]);
        }
        short8 v;
#pragma unroll
        for (int j = 0; j < 8; j++) v[j] = (short)f2bf(s[j]);
        *(short8*)(As + (e>>9)*PADW + (e&511)) = v;
    }
    __syncthreads();
    mfma_gemm<1>(g_WbO, bias, As, nullptr, out + base);
}

extern "C" void kernel_launch(void* const* d_in, const int* in_sizes, int n_in,
                              void* d_out, int out_size, void* d_ws, size_t ws_size,
                              hipStream_t stream)
{
    (void)in_sizes; (void)n_in; (void)out_size; (void)d_ws; (void)ws_size;
    const float* x      = (const float*)d_in[0];
    const float* lin_w  = (const float*)d_in[1];
    const float* lin_b  = (const float*)d_in[2];
    const float* weight = (const float*)d_in[3];
    const float* bias   = (const float*)d_in[4];
    float* out = (float*)d_out;

    hipLaunchKernelGGL(k_init0, dim3(512),  dim3(256), 0, stream, lin_w, weight);
    hipLaunchKernelGGL(k_init1, dim3(NBLK), dim3(TPB), 0, stream, x, lin_b);
    for (int k = 2; k < MAXIT; k++)
        hipLaunchKernelGGL(k_iter, dim3(NBLK), dim3(TPB), 0, stream, lin_b, k);
    hipLaunchKernelGGL(k_final, dim3(NBLK), dim3(TPB), 0, stream, bias, out);
}